// Round 8
// baseline (322.122 us; speedup 1.0000x reference)
//
#include <hip/hip_runtime.h>
#include <math.h>

#define N_CELLS 2048
#define D_IN 512
#define D_HID 1024
#define D_OUT 512

typedef __attribute__((ext_vector_type(8))) short bf16x8;
typedef __attribute__((ext_vector_type(4))) float f32x4;
typedef __attribute__((ext_vector_type(4))) short short4v;

#define MFMA16(a, b, c) __builtin_amdgcn_mfma_f32_16x16x32_bf16(a, b, c, 0, 0, 0)

__device__ __forceinline__ short f2bf(float f) {
  union { float f; unsigned u; } v; v.f = f;
  unsigned r = (v.u + 0x7FFFu + ((v.u >> 16) & 1u)) >> 16;
  return (short)r;
}

__device__ __forceinline__ void gl_lds16(const void* g, void* l) {
  __builtin_amdgcn_global_load_lds(
      (const __attribute__((address_space(1))) void*)g,
      (__attribute__((address_space(3))) void*)l, 16, 0, 0);
}

#define VMCNT(n) asm volatile("s_waitcnt vmcnt(" #n ")" ::: "memory")
#define BARRIER() asm volatile("s_barrier" ::: "memory")

// LDS bank-conflict swizzle (proven 0-conflict in R6): slot' = slot ^ ((row>>1)&3)
// applied on global SOURCE of global_load_lds (dest linear) and on ds_read slot.
#define SWZ(kq, row) ((kq) ^ (((row) >> 1) & 3))

// ---------------- prep: all weight transposes, vectorized stores ----------------
__global__ __launch_bounds__(256) void k_transpose_all(
    const float* __restrict__ w0, const float* __restrict__ w1,
    const float* __restrict__ w2, const float* __restrict__ w3,
    short* __restrict__ t0, short* __restrict__ t1,
    short* __restrict__ t2, short* __restrict__ t3,
    const float* __restrict__ ea_wr, const float* __restrict__ eg_wr,
    const float* __restrict__ ea_wi, const float* __restrict__ eg_wi,
    short* __restrict__ wdrT, short* __restrict__ wdiT) {
  const int k0 = blockIdx.x * 32, n0 = blockIdx.y * 32;
  const int c = threadIdx.x & 31, r4 = threadIdx.x >> 5;
  const int nl = threadIdx.x >> 3, kq = threadIdx.x & 7;
  if (blockIdx.z < 4) {
    const float* w = (blockIdx.z == 0) ? w0 : (blockIdx.z == 1) ? w1
                   : (blockIdx.z == 2) ? w2 : w3;
    short* wT = (blockIdx.z == 0) ? t0 : (blockIdx.z == 1) ? t1
              : (blockIdx.z == 2) ? t2 : t3;
    __shared__ float t[32][33];
#pragma unroll
    for (int i = 0; i < 4; ++i) {
      int kl = r4 * 4 + i;
      int k = k0 + kl;
      int srcrow = (k < 512) ? k : k + 1;
      t[kl][c] = w[(size_t)srcrow * D_HID + n0 + c];
    }
    __syncthreads();
    short4v v;
#pragma unroll
    for (int jv = 0; jv < 4; ++jv) v[jv] = f2bf(t[kq * 4 + jv][nl]);
    *(short4v*)&wT[(size_t)(n0 + nl) * 1536 + k0 + kq * 4] = v;
  } else {
    if (blockIdx.x >= 32 || blockIdx.y >= 16) return;
    __shared__ float tr[32][33], ti[32][33];
#pragma unroll
    for (int i = 0; i < 4; ++i) {
      int kl = r4 * 4 + i;
      int src = (512 + k0 + kl) * D_OUT + n0 + c;
      tr[kl][c] = ea_wr[src] - eg_wr[src];
      ti[kl][c] = ea_wi[src] - eg_wi[src];
    }
    __syncthreads();
    short4v vr, vi;
#pragma unroll
    for (int jv = 0; jv < 4; ++jv) {
      vr[jv] = f2bf(tr[kq * 4 + jv][nl]);
      vi[jv] = f2bf(ti[kq * 4 + jv][nl]);
    }
    size_t dst = (size_t)(n0 + nl) * D_HID + k0 + kq * 4;
    *(short4v*)&wdrT[dst] = vr;
    *(short4v*)&wdiT[dst] = vi;
  }
}

// h fp32 -> bf16 + |h| into gatesA cols 512..1535 ; also zero tens
__global__ __launch_bounds__(256) void k_prep_h(
    const float* __restrict__ h_re, const float* __restrict__ h_im,
    short* __restrict__ hbre, short* __restrict__ hbim, short* __restrict__ gatesA,
    float* __restrict__ tens) {
  if (threadIdx.x == 0) tens[blockIdx.x] = 0.f;
  int idx4 = (blockIdx.x * 256 + threadIdx.x) * 4;
  int m = idx4 >> 10, n = idx4 & 1023;
  float4 hr = *(const float4*)&h_re[idx4];
  float4 hi = *(const float4*)&h_im[idx4];
  short4v br, bi, bm;
  br.x = f2bf(hr.x); br.y = f2bf(hr.y); br.z = f2bf(hr.z); br.w = f2bf(hr.w);
  bi.x = f2bf(hi.x); bi.y = f2bf(hi.y); bi.z = f2bf(hi.z); bi.w = f2bf(hi.w);
  bm.x = f2bf(sqrtf(hr.x * hr.x + hi.x * hi.x));
  bm.y = f2bf(sqrtf(hr.y * hr.y + hi.y * hi.y));
  bm.z = f2bf(sqrtf(hr.z * hr.z + hi.z * hi.z));
  bm.w = f2bf(sqrtf(hr.w * hr.w + hi.w * hi.w));
  *(short4v*)&hbre[idx4] = br;
  *(short4v*)&hbim[idx4] = bi;
  *(short4v*)&gatesA[(size_t)m * 1536 + 512 + n] = bm;
}

// ---------------- bias from x: split-K stage 1 (reduce folded into k_engine) ----
__global__ __launch_bounds__(256) void k_bias_part(
    const float* __restrict__ x,
    const float* __restrict__ ea_wr, const float* __restrict__ ea_wi,
    const float* __restrict__ eg_wr, const float* __restrict__ eg_wi,
    float* __restrict__ bpartr, float* __restrict__ bparti) {
  int n = blockIdx.x * 256 + threadIdx.x;
  int kc = blockIdx.y;
  float sr = 0.f, si = 0.f;
  for (int i = 0; i < 64; ++i) {
    int k = kc * 64 + i;
    float xv = x[k];
    int idx = k * D_OUT + n;
    sr += xv * (ea_wr[idx] - eg_wr[idx]);
    si += xv * (ea_wi[idx] - eg_wi[idx]);
  }
  bpartr[kc * D_OUT + n] = sr;
  bparti[kc * D_OUT + n] = si;
}

// ---------------- MFMA GEMM 1: complex engine, tile 64x64, BK=64 (R2 struct) ----
// 4-way complex reuse; dbuf; vmcnt(8); swizzle; bias_red folded into epilogue.
__global__ __launch_bounds__(256) void k_engine(
    const short* __restrict__ hbre, const short* __restrict__ hbim,
    const short* __restrict__ wdrT, const short* __restrict__ wdiT,
    const float* __restrict__ bpartr, const float* __restrict__ bparti,
    const float* __restrict__ ea_br, const float* __restrict__ ea_bi,
    const float* __restrict__ eg_br, const float* __restrict__ eg_bi,
    float* __restrict__ ore, float* __restrict__ oim,
    short* __restrict__ gatesA, short* __restrict__ candAre, short* __restrict__ candAim,
    float* __restrict__ tens) {
  __shared__ short Ar[2][4096], Ai[2][4096];
  __shared__ short Brs[2][4096], Bis[2][4096];
  const int m0 = blockIdx.x * 64, n0 = blockIdx.y * 64;
  const int tid = threadIdx.x;
  const int wid = tid >> 6, lane = tid & 63;
  const int quad = lane >> 4, lcol = lane & 15;
  const int wm = (wid >> 1) * 32, wn = (wid & 1) * 32;
  f32x4 accre[2][2], accim[2][2];
#pragma unroll
  for (int mt = 0; mt < 2; ++mt)
#pragma unroll
    for (int nt = 0; nt < 2; ++nt) {
      accre[mt][nt] = (f32x4){0.f, 0.f, 0.f, 0.f};
      accim[mt][nt] = (f32x4){0.f, 0.f, 0.f, 0.f};
    }
  auto stage = [&](int buf, int k0) {
#pragma unroll
    for (int i = 0; i < 2; ++i) {
      int c = i * 256 + tid;  // 0..511
      int kh = c >> 8, row = (c >> 2) & 63, kq = c & 3;
      size_t off = k0 + kh * 32 + SWZ(kq, row) * 8;
      size_t ga = (size_t)(m0 + row) * D_HID + off;
      size_t gb = (size_t)(n0 + row) * D_HID + off;
      gl_lds16(hbre + ga, &Ar[buf][c * 8]);
      gl_lds16(hbim + ga, &Ai[buf][c * 8]);
      gl_lds16(wdrT + gb, &Brs[buf][c * 8]);
      gl_lds16(wdiT + gb, &Bis[buf][c * 8]);
    }
  };
  stage(0, 0);
  for (int t = 0; t < 16; ++t) {
    const int cur = t & 1;
    if (t < 15) {
      stage(cur ^ 1, (t + 1) * 64);
      VMCNT(8);
    } else {
      VMCNT(0);
    }
    BARRIER();
#pragma unroll
    for (int kh = 0; kh < 2; ++kh) {
      bf16x8 ar[2], ai[2], ain[2], br[2], bi[2];
#pragma unroll
      for (int mt = 0; mt < 2; ++mt) {
        int row = wm + mt * 16 + lcol;
        int aoff = kh * 2048 + row * 32 + SWZ(quad, row) * 8;
        ar[mt] = *(const bf16x8*)&Ar[cur][aoff];
        ai[mt] = *(const bf16x8*)&Ai[cur][aoff];
#pragma unroll
        for (int jj = 0; jj < 8; ++jj) ain[mt][jj] = ai[mt][jj] ^ (short)0x8000;
      }
#pragma unroll
      for (int nt = 0; nt < 2; ++nt) {
        int row = wn + nt * 16 + lcol;
        int boff = kh * 2048 + row * 32 + SWZ(quad, row) * 8;
        br[nt] = *(const bf16x8*)&Brs[cur][boff];
        bi[nt] = *(const bf16x8*)&Bis[cur][boff];
      }
#pragma unroll
      for (int mt = 0; mt < 2; ++mt)
#pragma unroll
        for (int nt = 0; nt < 2; ++nt) {
          accre[mt][nt] = MFMA16(ar[mt], br[nt], accre[mt][nt]);
          accre[mt][nt] = MFMA16(ain[mt], bi[nt], accre[mt][nt]);
          accim[mt][nt] = MFMA16(ar[mt], bi[nt], accim[mt][nt]);
          accim[mt][nt] = MFMA16(ai[mt], br[nt], accim[mt][nt]);
        }
    }
    if (t < 15) BARRIER();
  }
  // folded bias_red: bias per n-col (2 cols per lane)
  float bre[2], bim[2];
#pragma unroll
  for (int nt = 0; nt < 2; ++nt) {
    int n = n0 + wn + nt * 16 + lcol;
    float sr = 0.f, si = 0.f;
#pragma unroll
    for (int kc = 0; kc < 8; ++kc) {
      sr += bpartr[kc * D_OUT + n];
      si += bparti[kc * D_OUT + n];
    }
    float brd = ea_br[n] - eg_br[n];
    float bid = ea_bi[n] - eg_bi[n];
    bre[nt] = sr + brd - bid;
    bim[nt] = si + brd + bid;
  }
#pragma unroll
  for (int mt = 0; mt < 2; ++mt)
#pragma unroll
    for (int r = 0; r < 4; ++r) {
      int m = m0 + wm + mt * 16 + quad * 4 + r;
      float t = 0.f;
#pragma unroll
      for (int nt = 0; nt < 2; ++nt) {
        int n = n0 + wn + nt * 16 + lcol;
        float cre = accre[mt][nt][r] + bre[nt];
        float cim = accim[mt][nt][r] + bim[nt];
        t += cre * cre + cim * cim;
        ore[(size_t)m * D_OUT + n] = cre;
        oim[(size_t)m * D_OUT + n] = cim;
        gatesA[(size_t)m * 1536 + n] = f2bf(sqrtf(cre * cre + cim * cim));
        candAre[(size_t)m * 1536 + n] = f2bf(cre);
        candAim[(size_t)m * 1536 + n] = f2bf(cim);
      }
#pragma unroll
      for (int off = 1; off < 16; off <<= 1) t += __shfl_xor(t, off);
      if (lcol == 0) atomicAdd(&tens[m], t * (1.f / 512.f));
    }
}

// ---------------- MFMA GEMM 2: gates z+r FUSED (shared A), tile 128x64 (R2) ----
__global__ __launch_bounds__(256) void k_gates(
    const short* __restrict__ gatesA,
    const short* __restrict__ gzwT, const short* __restrict__ grwT,
    const float* __restrict__ gz_w, const float* __restrict__ gz_b,
    const float* __restrict__ gr_w, const float* __restrict__ gr_b,
    const float* __restrict__ tens,
    const float* __restrict__ h_re, const float* __restrict__ h_im,
    float* __restrict__ zbuf,
    short* __restrict__ candAre, short* __restrict__ candAim) {
  __shared__ short As[2][8192];
  __shared__ short Bz[2][4096];
  __shared__ short Br[2][4096];
  const int m0 = blockIdx.x * 128, n0 = blockIdx.y * 64;
  const int tid = threadIdx.x;
  const int wid = tid >> 6, lane = tid & 63;
  const int quad = lane >> 4, lcol = lane & 15;
  const int wm = (wid >> 1) * 64, wn = (wid & 1) * 32;
  f32x4 accz[4][2], accr[4][2];
#pragma unroll
  for (int mt = 0; mt < 4; ++mt)
#pragma unroll
    for (int nt = 0; nt < 2; ++nt) {
      accz[mt][nt] = (f32x4){0.f, 0.f, 0.f, 0.f};
      accr[mt][nt] = (f32x4){0.f, 0.f, 0.f, 0.f};
    }
  auto stage = [&](int buf, int k0) {
#pragma unroll
    for (int i = 0; i < 4; ++i) {
      int c = i * 256 + tid;  // 0..1023
      int kh = c >> 9, row = (c >> 2) & 127, kq = c & 3;
      gl_lds16(gatesA + (size_t)(m0 + row) * 1536 + k0 + kh * 32 + SWZ(kq, row) * 8,
               &As[buf][c * 8]);
    }
#pragma unroll
    for (int i = 0; i < 2; ++i) {
      int c = i * 256 + tid;  // 0..511
      int kh = c >> 8, row = (c >> 2) & 63, kq = c & 3;
      size_t g = (size_t)(n0 + row) * 1536 + k0 + kh * 32 + SWZ(kq, row) * 8;
      gl_lds16(gzwT + g, &Bz[buf][c * 8]);
      gl_lds16(grwT + g, &Br[buf][c * 8]);
    }
  };
  stage(0, 0);
  for (int t = 0; t < 24; ++t) {
    const int cur = t & 1;
    if (t < 23) {
      stage(cur ^ 1, (t + 1) * 64);
      VMCNT(8);
    } else {
      VMCNT(0);
    }
    BARRIER();
#pragma unroll
    for (int kh = 0; kh < 2; ++kh) {
      bf16x8 a[4], bz[2], br[2];
#pragma unroll
      for (int mt = 0; mt < 4; ++mt) {
        int row = wm + mt * 16 + lcol;
        a[mt] = *(const bf16x8*)&As[cur][kh * 4096 + row * 32 + SWZ(quad, row) * 8];
      }
#pragma unroll
      for (int nt = 0; nt < 2; ++nt) {
        int row = wn + nt * 16 + lcol;
        int boff = kh * 2048 + row * 32 + SWZ(quad, row) * 8;
        bz[nt] = *(const bf16x8*)&Bz[cur][boff];
        br[nt] = *(const bf16x8*)&Br[cur][boff];
      }
#pragma unroll
      for (int mt = 0; mt < 4; ++mt)
#pragma unroll
        for (int nt = 0; nt < 2; ++nt) {
          accz[mt][nt] = MFMA16(a[mt], bz[nt], accz[mt][nt]);
          accr[mt][nt] = MFMA16(a[mt], br[nt], accr[mt][nt]);
        }
    }
    if (t < 23) BARRIER();
  }
#pragma unroll
  for (int mt = 0; mt < 4; ++mt)
#pragma unroll
    for (int nt = 0; nt < 2; ++nt)
#pragma unroll
      for (int r = 0; r < 4; ++r) {
        int m = m0 + wm + mt * 16 + quad * 4 + r;
        int n = n0 + wn + nt * 16 + lcol;
        float tv = tens[m];
        float zp = accz[mt][nt][r] + gz_b[n] + tv * gz_w[(size_t)512 * D_HID + n];
        zbuf[(size_t)m * D_HID + n] = 1.f / (1.f + expf(-zp));
        float rp = accr[mt][nt][r] + gr_b[n] + tv * gr_w[(size_t)512 * D_HID + n];
        float rr = 1.f / (1.f + expf(-rp));
        candAre[(size_t)m * 1536 + 512 + n] = f2bf(rr * h_re[(size_t)m * D_HID + n]);
        candAim[(size_t)m * 1536 + 512 + n] = f2bf(rr * h_im[(size_t)m * D_HID + n]);
      }
}

// ---------------- MFMA GEMM 3: candidate + GRU blend, tile 128x128 (R2) --------
__global__ __launch_bounds__(512) void k_cand(
    const short* __restrict__ candAre, const short* __restrict__ candAim,
    const short* __restrict__ ghrwT, const short* __restrict__ ghiwT,
    const float* __restrict__ ghr_b, const float* __restrict__ ghi_b,
    const float* __restrict__ ghr_w,
    const float* __restrict__ tens, const float* __restrict__ zbuf,
    const float* __restrict__ h_re, const float* __restrict__ h_im,
    float* __restrict__ nhre, float* __restrict__ nhim) {
  __shared__ short As[2][8192];
  __shared__ short Bs[2][8192];
  const int is_re = (blockIdx.z == 0);
  const short* A = is_re ? candAre : candAim;
  const short* Bt = is_re ? ghrwT : ghiwT;
  const float* bias = is_re ? ghr_b : ghi_b;
  const float* h = is_re ? h_re : h_im;
  float* outp = is_re ? nhre : nhim;
  const int m0 = blockIdx.x * 128, n0 = blockIdx.y * 128;
  const int tid = threadIdx.x;
  const int wid = tid >> 6, lane = tid & 63;
  const int quad = lane >> 4, lcol = lane & 15;
  const int wm = (wid >> 2) * 64, wn = (wid & 3) * 32;
  f32x4 acc[4][2];
#pragma unroll
  for (int mt = 0; mt < 4; ++mt)
#pragma unroll
    for (int nt = 0; nt < 2; ++nt) acc[mt][nt] = (f32x4){0.f, 0.f, 0.f, 0.f};
  auto stage = [&](int buf, int k0) {
#pragma unroll
    for (int i = 0; i < 2; ++i) {
      int c = i * 512 + tid;  // 0..1023
      int kh = c >> 9, row = (c >> 2) & 127, kq = c & 3;
      size_t off = k0 + kh * 32 + SWZ(kq, row) * 8;
      gl_lds16(A + (size_t)(m0 + row) * 1536 + off, &As[buf][c * 8]);
      gl_lds16(Bt + (size_t)(n0 + row) * 1536 + off, &Bs[buf][c * 8]);
    }
  };
  stage(0, 0);
  for (int t = 0; t < 24; ++t) {
    const int cur = t & 1;
    if (t < 23) {
      stage(cur ^ 1, (t + 1) * 64);
      VMCNT(4);
    } else {
      VMCNT(0);
    }
    BARRIER();
#pragma unroll
    for (int kh = 0; kh < 2; ++kh) {
      bf16x8 a[4], b[2];
#pragma unroll
      for (int mt = 0; mt < 4; ++mt) {
        int row = wm + mt * 16 + lcol;
        a[mt] = *(const bf16x8*)&As[cur][kh * 4096 + row * 32 + SWZ(quad, row) * 8];
      }
#pragma unroll
      for (int nt = 0; nt < 2; ++nt) {
        int row = wn + nt * 16 + lcol;
        b[nt] = *(const bf16x8*)&Bs[cur][kh * 4096 + row * 32 + SWZ(quad, row) * 8];
      }
#pragma unroll
      for (int mt = 0; mt < 4; ++mt)
#pragma unroll
        for (int nt = 0; nt < 2; ++nt)
          acc[mt][nt] = MFMA16(a[mt], b[nt], acc[mt][nt]);
    }
    if (t < 23) BARRIER();
  }
#pragma unroll
  for (int mt = 0; mt < 4; ++mt)
#pragma unroll
    for (int nt = 0; nt < 2; ++nt)
#pragma unroll
      for (int r = 0; r < 4; ++r) {
        int m = m0 + wm + mt * 16 + quad * 4 + r;
        int n = n0 + wn + nt * 16 + lcol;
        float pre = acc[mt][nt][r] + bias[n];
        if (is_re) pre += tens[m] * ghr_w[(size_t)512 * D_HID + n];
        float cand = tanhf(pre);
        float z = zbuf[(size_t)m * D_HID + n];
        float hv = h[(size_t)m * D_HID + n];
        outp[(size_t)m * D_HID + n] = (1.f - z) * hv + z * cand;
      }
}

// ---------------- faction sync: two-stage ----------------
__global__ __launch_bounds__(256) void k_fsum_part(
    const float* __restrict__ nhre, const float* __restrict__ nhim,
    float* __restrict__ fpart) {
  int f = blockIdx.x >> 3, rc = blockIdx.x & 7, comp = blockIdx.y;
  const float* src = comp ? nhim : nhre;
  int row0 = f * 256 + rc * 32;
#pragma unroll
  for (int nc = 0; nc < 4; ++nc) {
    int n = nc * 256 + threadIdx.x;
    float s = 0.f;
    const float* base = src + (size_t)row0 * D_HID + n;
    for (int jj = 0; jj < 32; ++jj) s += base[(size_t)jj * D_HID];
    fpart[((size_t)comp * 64 + blockIdx.x) * D_HID + n] = s;
  }
}

__global__ __launch_bounds__(256) void k_fsum_red(
    const float* __restrict__ fpart,
    float* __restrict__ fsre, float* __restrict__ fsim,
    float* __restrict__ gre, float* __restrict__ gim) {
  int n = blockIdx.x * 256 + threadIdx.x;
  int comp = blockIdx.y;
  float* fs = comp ? fsim : fsre;
  float* g = comp ? gim : gre;
  float gsum = 0.f;
#pragma unroll
  for (int f = 0; f < 8; ++f) {
    float sf = 0.f;
#pragma unroll
    for (int rc = 0; rc < 8; ++rc)
      sf += fpart[((size_t)comp * 64 + f * 8 + rc) * D_HID + n];
    fs[f * D_HID + n] = sf;
    gsum += sf;
  }
  g[n] = gsum * (1.f / 2048.f);
}

__global__ __launch_bounds__(256) void k_sync(
    float* __restrict__ nhre, float* __restrict__ nhim,
    const float* __restrict__ fsre, const float* __restrict__ fsim,
    const float* __restrict__ gre, const float* __restrict__ gim,
    const int* __restrict__ step) {
  int idx = blockIdx.x * 256 + threadIdx.x;
  int m = idx >> 10, n = idx & 1023;
  int f = m >> 8;
  float vr = nhre[idx], vi = nhim[idx];
  vr = 0.85f * vr + 0.15f * (fsre[f * D_HID + n] * (1.f / 256.f));
  vi = 0.85f * vi + 0.15f * (fsim[f * D_HID + n] * (1.f / 256.f));
  if (step[0] > 5 && (m & 255) < 64) {
    vr = 0.85f * vr + 0.15f * gre[n];
    vi = 0.85f * vi + 0.15f * gim[n];
  }
  nhre[idx] = vr;
  nhim[idx] = vi;
}

// ---------------- combine stage1 with fused softmax stats ----------------
// Each block redundantly computes softmax stats over tens[2048] (trivial);
// block (0,0) additionally writes meanT. k_stats launch eliminated.
__global__ __launch_bounds__(256) void k_comb_part(
    const float* __restrict__ ore, const float* __restrict__ oim,
    const float* __restrict__ tens, float* __restrict__ cpart,
    float* __restrict__ meanT_out) {
  __shared__ float redv[4];
  __shared__ float s_max, s_inv, s_tot;
  __shared__ float wl[128];
  int tid = threadIdx.x;
  int wid = tid >> 6, lane = tid & 63;
  float lv[8];
  float mx = -1e30f;
#pragma unroll
  for (int j2 = 0; j2 < 8; ++j2) {
    lv[j2] = tens[tid + j2 * 256];
    mx = fmaxf(mx, lv[j2]);
  }
  for (int off = 32; off; off >>= 1) mx = fmaxf(mx, __shfl_xor(mx, off));
  if (lane == 0) redv[wid] = mx;
  __syncthreads();
  if (tid == 0)
    s_max = fmaxf(fmaxf(redv[0], redv[1]), fmaxf(redv[2], redv[3]));
  __syncthreads();
  mx = s_max;
  float se = 0.f, st = 0.f;
#pragma unroll
  for (int j2 = 0; j2 < 8; ++j2) { se += expf(lv[j2] - mx); st += lv[j2]; }
  for (int off = 32; off; off >>= 1) se += __shfl_xor(se, off);
  if (lane == 0) redv[wid] = se;
  __syncthreads();
  if (tid == 0) s_inv = 1.f / (redv[0] + redv[1] + redv[2] + redv[3]);
  __syncthreads();
  if (blockIdx.x == 0 && blockIdx.y == 0) {
    for (int off = 32; off; off >>= 1) st += __shfl_xor(st, off);
    if (lane == 0) redv[wid] = st;
    __syncthreads();
    if (tid == 0)
      meanT_out[0] = (redv[0] + redv[1] + redv[2] + redv[3]) * (1.f / 2048.f);
  }
  int mc = blockIdx.y;
  if (tid < 128) wl[tid] = expf(tens[mc * 128 + tid] - mx) * s_inv;
  __syncthreads();
  int j = blockIdx.x * 256 + tid;
  const float* src = (j < 512) ? ore : oim;
  int col = j & 511;
  float s = 0.f;
  for (int i = 0; i < 128; ++i) {
    int m = mc * 128 + i;
    s += wl[i] * src[(size_t)m * D_OUT + col];
  }
  cpart[(size_t)mc * 1024 + j] = s;
}

// ---------------- pred: comb reduction + GEMV + bias in ONE kernel ----------------
__global__ __launch_bounds__(256) void k_pred(
    const float* __restrict__ cpart, const float* __restrict__ oh_w,
    const float* __restrict__ oh_b, float* __restrict__ pred) {
  __shared__ float combs[1024];
  int tid = threadIdx.x;
#pragma unroll
  for (int jj = 0; jj < 4; ++jj) {
    int j = tid + jj * 256;
    float s = 0.f;
#pragma unroll
    for (int mc = 0; mc < 16; ++mc) s += cpart[(size_t)mc * 1024 + j];
    combs[j] = s;
  }
  __syncthreads();
  int n = blockIdx.x * 256 + tid;
  float s = oh_b[n];
  for (int j = 0; j < 1024; ++j) s += combs[j] * oh_w[(size_t)j * D_IN + n];
  pred[n] = s;
}

// ---------------- launcher ----------------
extern "C" void kernel_launch(void* const* d_in, const int* in_sizes, int n_in,
                              void* d_out, int out_size, void* d_ws, size_t ws_size,
                              hipStream_t stream) {
  const float* x     = (const float*)d_in[0];
  const float* h_re  = (const float*)d_in[1];
  const float* h_im  = (const float*)d_in[2];
  const float* ea_wr = (const float*)d_in[3];
  const float* ea_br = (const float*)d_in[4];
  const float* ea_wi = (const float*)d_in[5];
  const float* ea_bi = (const float*)d_in[6];
  const float* eg_wr = (const float*)d_in[7];
  const float* eg_br = (const float*)d_in[8];
  const float* eg_wi = (const float*)d_in[9];
  const float* eg_bi = (const float*)d_in[10];
  const float* gz_w  = (const float*)d_in[11];
  const float* gz_b  = (const float*)d_in[12];
  const float* gr_w  = (const float*)d_in[13];
  const float* gr_b  = (const float*)d_in[14];
  const float* ghr_w = (const float*)d_in[15];
  const float* ghr_b = (const float*)d_in[16];
  const float* ghi_w = (const float*)d_in[17];
  const float* ghi_b = (const float*)d_in[18];
  const float* oh_w  = (const float*)d_in[19];
  const float* oh_b  = (const float*)d_in[20];
  const int*   step  = (const int*)d_in[21];

  float* out = (float*)d_out;
  float* pred_out  = out;
  float* meanT_out = out + 512;
  float* nhre_out  = out + 513;
  float* nhim_out  = out + 513 + N_CELLS * D_HID;

  char* p = (char*)d_ws;
  auto carve = [&](size_t bytes) { char* r = p; p += (bytes + 255) & ~(size_t)255; return r; };
  short* wdrT   = (short*)carve(512 * 1024 * 2);
  short* wdiT   = (short*)carve(512 * 1024 * 2);
  short* gzwT   = (short*)carve(1024 * 1536 * 2);
  short* grwT   = (short*)carve(1024 * 1536 * 2);
  short* ghrwT  = (short*)carve(1024 * 1536 * 2);
  short* ghiwT  = (short*)carve(1024 * 1536 * 2);
  short* hbre   = (short*)carve(2048 * 1024 * 2);
  short* hbim   = (short*)carve(2048 * 1024 * 2);
  short* gatesA = (short*)carve((size_t)2048 * 1536 * 2);
  short* candAre= (short*)carve((size_t)2048 * 1536 * 2);
  short* candAim= (short*)carve((size_t)2048 * 1536 * 2);
  float* ore    = (float*)carve(2048 * 512 * 4);
  float* oim    = (float*)carve(2048 * 512 * 4);
  float* zbuf   = (float*)carve((size_t)2048 * 1024 * 4);
  float* bpartr = (float*)carve(8 * 512 * 4);
  float* bparti = (float*)carve(8 * 512 * 4);
  float* tens   = (float*)carve(2048 * 4);
  float* fpart  = (float*)carve(2 * 64 * 1024 * 4);
  float* fsre   = (float*)carve(8 * 1024 * 4);
  float* fsim   = (float*)carve(8 * 1024 * 4);
  float* gre    = (float*)carve(1024 * 4);
  float* gim    = (float*)carve(1024 * 4);
  float* cpart  = (float*)carve(16 * 1024 * 4);

  hipLaunchKernelGGL(k_transpose_all, dim3(48, 32, 5), dim3(256), 0, stream,
                     gz_w, gr_w, ghr_w, ghi_w, gzwT, grwT, ghrwT, ghiwT,
                     ea_wr, eg_wr, ea_wi, eg_wi, wdrT, wdiT);
  hipLaunchKernelGGL(k_prep_h, dim3(2048), dim3(256), 0, stream,
                     h_re, h_im, hbre, hbim, gatesA, tens);
  hipLaunchKernelGGL(k_bias_part, dim3(2, 8), dim3(256), 0, stream,
                     x, ea_wr, ea_wi, eg_wr, eg_wi, bpartr, bparti);
  hipLaunchKernelGGL(k_engine, dim3(32, 8), dim3(256), 0, stream,
                     hbre, hbim, wdrT, wdiT, bpartr, bparti,
                     ea_br, ea_bi, eg_br, eg_bi,
                     ore, oim, gatesA, candAre, candAim, tens);
  hipLaunchKernelGGL(k_gates, dim3(16, 16), dim3(256), 0, stream,
                     gatesA, gzwT, grwT, gz_w, gz_b, gr_w, gr_b, tens,
                     h_re, h_im, zbuf, candAre, candAim);
  hipLaunchKernelGGL(k_cand, dim3(16, 8, 2), dim3(512), 0, stream,
                     candAre, candAim, ghrwT, ghiwT, ghr_b, ghi_b, ghr_w,
                     tens, zbuf, h_re, h_im, nhre_out, nhim_out);
  hipLaunchKernelGGL(k_fsum_part, dim3(64, 2), dim3(256), 0, stream,
                     nhre_out, nhim_out, fpart);
  hipLaunchKernelGGL(k_fsum_red, dim3(4, 2), dim3(256), 0, stream,
                     fpart, fsre, fsim, gre, gim);
  hipLaunchKernelGGL(k_sync, dim3((N_CELLS * D_HID) / 256), dim3(256), 0, stream,
                     nhre_out, nhim_out, fsre, fsim, gre, gim, step);
  hipLaunchKernelGGL(k_comb_part, dim3(4, 16), dim3(256), 0, stream,
                     ore, oim, tens, cpart, meanT_out);
  hipLaunchKernelGGL(k_pred, dim3(2), dim3(256), 0, stream,
                     cpart, oh_w, oh_b, pred_out);
}

// Round 9
// 292.990 us; speedup vs baseline: 1.0994x; 1.0994x over previous
//
#include <hip/hip_runtime.h>
#include <math.h>

#define N_CELLS 2048
#define D_IN 512
#define D_HID 1024
#define D_OUT 512

typedef __attribute__((ext_vector_type(8))) short bf16x8;
typedef __attribute__((ext_vector_type(4))) float f32x4;
typedef __attribute__((ext_vector_type(4))) short short4v;

#define MFMA16(a, b, c) __builtin_amdgcn_mfma_f32_16x16x32_bf16(a, b, c, 0, 0, 0)

__device__ __forceinline__ short f2bf(float f) {
  union { float f; unsigned u; } v; v.f = f;
  unsigned r = (v.u + 0x7FFFu + ((v.u >> 16) & 1u)) >> 16;
  return (short)r;
}

__device__ __forceinline__ void gl_lds16(const void* g, void* l) {
  __builtin_amdgcn_global_load_lds(
      (const __attribute__((address_space(1))) void*)g,
      (__attribute__((address_space(3))) void*)l, 16, 0, 0);
}

#define VMCNT(n) asm volatile("s_waitcnt vmcnt(" #n ")" ::: "memory")
#define BARRIER() asm volatile("s_barrier" ::: "memory")

// LDS bank-conflict swizzle (proven 0-conflict in R6): slot' = slot ^ ((row>>1)&3)
// applied on global SOURCE of global_load_lds (dest linear) and on ds_read slot.
#define SWZ(kq, row) ((kq) ^ (((row) >> 1) & 3))

// ---------------- prep: all weight transposes, vectorized stores ----------------
__global__ __launch_bounds__(256) void k_transpose_all(
    const float* __restrict__ w0, const float* __restrict__ w1,
    const float* __restrict__ w2, const float* __restrict__ w3,
    short* __restrict__ t0, short* __restrict__ t1,
    short* __restrict__ t2, short* __restrict__ t3,
    const float* __restrict__ ea_wr, const float* __restrict__ eg_wr,
    const float* __restrict__ ea_wi, const float* __restrict__ eg_wi,
    short* __restrict__ wdrT, short* __restrict__ wdiT) {
  const int k0 = blockIdx.x * 32, n0 = blockIdx.y * 32;
  const int c = threadIdx.x & 31, r4 = threadIdx.x >> 5;
  const int nl = threadIdx.x >> 3, kq = threadIdx.x & 7;
  if (blockIdx.z < 4) {
    const float* w = (blockIdx.z == 0) ? w0 : (blockIdx.z == 1) ? w1
                   : (blockIdx.z == 2) ? w2 : w3;
    short* wT = (blockIdx.z == 0) ? t0 : (blockIdx.z == 1) ? t1
              : (blockIdx.z == 2) ? t2 : t3;
    __shared__ float t[32][33];
#pragma unroll
    for (int i = 0; i < 4; ++i) {
      int kl = r4 * 4 + i;
      int k = k0 + kl;
      int srcrow = (k < 512) ? k : k + 1;
      t[kl][c] = w[(size_t)srcrow * D_HID + n0 + c];
    }
    __syncthreads();
    short4v v;
#pragma unroll
    for (int jv = 0; jv < 4; ++jv) v[jv] = f2bf(t[kq * 4 + jv][nl]);
    *(short4v*)&wT[(size_t)(n0 + nl) * 1536 + k0 + kq * 4] = v;
  } else {
    if (blockIdx.x >= 32 || blockIdx.y >= 16) return;
    __shared__ float tr[32][33], ti[32][33];
#pragma unroll
    for (int i = 0; i < 4; ++i) {
      int kl = r4 * 4 + i;
      int src = (512 + k0 + kl) * D_OUT + n0 + c;
      tr[kl][c] = ea_wr[src] - eg_wr[src];
      ti[kl][c] = ea_wi[src] - eg_wi[src];
    }
    __syncthreads();
    short4v vr, vi;
#pragma unroll
    for (int jv = 0; jv < 4; ++jv) {
      vr[jv] = f2bf(tr[kq * 4 + jv][nl]);
      vi[jv] = f2bf(ti[kq * 4 + jv][nl]);
    }
    size_t dst = (size_t)(n0 + nl) * D_HID + k0 + kq * 4;
    *(short4v*)&wdrT[dst] = vr;
    *(short4v*)&wdiT[dst] = vi;
  }
}

// h fp32 -> bf16 + |h| into gatesA cols 512..1535 ; also zero tens
__global__ __launch_bounds__(256) void k_prep_h(
    const float* __restrict__ h_re, const float* __restrict__ h_im,
    short* __restrict__ hbre, short* __restrict__ hbim, short* __restrict__ gatesA,
    float* __restrict__ tens) {
  if (threadIdx.x == 0) tens[blockIdx.x] = 0.f;
  int idx4 = (blockIdx.x * 256 + threadIdx.x) * 4;
  int m = idx4 >> 10, n = idx4 & 1023;
  float4 hr = *(const float4*)&h_re[idx4];
  float4 hi = *(const float4*)&h_im[idx4];
  short4v br, bi, bm;
  br.x = f2bf(hr.x); br.y = f2bf(hr.y); br.z = f2bf(hr.z); br.w = f2bf(hr.w);
  bi.x = f2bf(hi.x); bi.y = f2bf(hi.y); bi.z = f2bf(hi.z); bi.w = f2bf(hi.w);
  bm.x = f2bf(sqrtf(hr.x * hr.x + hi.x * hi.x));
  bm.y = f2bf(sqrtf(hr.y * hr.y + hi.y * hi.y));
  bm.z = f2bf(sqrtf(hr.z * hr.z + hi.z * hi.z));
  bm.w = f2bf(sqrtf(hr.w * hr.w + hi.w * hi.w));
  *(short4v*)&hbre[idx4] = br;
  *(short4v*)&hbim[idx4] = bi;
  *(short4v*)&gatesA[(size_t)m * 1536 + 512 + n] = bm;
}

// ---------------- bias from x: split-K stage 1 (reduce folded into k_engine) ----
__global__ __launch_bounds__(256) void k_bias_part(
    const float* __restrict__ x,
    const float* __restrict__ ea_wr, const float* __restrict__ ea_wi,
    const float* __restrict__ eg_wr, const float* __restrict__ eg_wi,
    float* __restrict__ bpartr, float* __restrict__ bparti) {
  int n = blockIdx.x * 256 + threadIdx.x;
  int kc = blockIdx.y;
  float sr = 0.f, si = 0.f;
  for (int i = 0; i < 64; ++i) {
    int k = kc * 64 + i;
    float xv = x[k];
    int idx = k * D_OUT + n;
    sr += xv * (ea_wr[idx] - eg_wr[idx]);
    si += xv * (ea_wi[idx] - eg_wi[idx]);
  }
  bpartr[kc * D_OUT + n] = sr;
  bparti[kc * D_OUT + n] = si;
}

// ---------------- MFMA GEMM 1: complex engine, tile 64x64, BK=64 (R2 struct) ----
// 4-way complex reuse; dbuf; vmcnt(8); swizzle; bias_red folded into epilogue.
__global__ __launch_bounds__(256) void k_engine(
    const short* __restrict__ hbre, const short* __restrict__ hbim,
    const short* __restrict__ wdrT, const short* __restrict__ wdiT,
    const float* __restrict__ bpartr, const float* __restrict__ bparti,
    const float* __restrict__ ea_br, const float* __restrict__ ea_bi,
    const float* __restrict__ eg_br, const float* __restrict__ eg_bi,
    float* __restrict__ ore, float* __restrict__ oim,
    short* __restrict__ gatesA, short* __restrict__ candAre, short* __restrict__ candAim,
    float* __restrict__ tens) {
  __shared__ short Ar[2][4096], Ai[2][4096];
  __shared__ short Brs[2][4096], Bis[2][4096];
  const int m0 = blockIdx.x * 64, n0 = blockIdx.y * 64;
  const int tid = threadIdx.x;
  const int wid = tid >> 6, lane = tid & 63;
  const int quad = lane >> 4, lcol = lane & 15;
  const int wm = (wid >> 1) * 32, wn = (wid & 1) * 32;
  f32x4 accre[2][2], accim[2][2];
#pragma unroll
  for (int mt = 0; mt < 2; ++mt)
#pragma unroll
    for (int nt = 0; nt < 2; ++nt) {
      accre[mt][nt] = (f32x4){0.f, 0.f, 0.f, 0.f};
      accim[mt][nt] = (f32x4){0.f, 0.f, 0.f, 0.f};
    }
  auto stage = [&](int buf, int k0) {
#pragma unroll
    for (int i = 0; i < 2; ++i) {
      int c = i * 256 + tid;  // 0..511
      int kh = c >> 8, row = (c >> 2) & 63, kq = c & 3;
      size_t off = k0 + kh * 32 + SWZ(kq, row) * 8;
      size_t ga = (size_t)(m0 + row) * D_HID + off;
      size_t gb = (size_t)(n0 + row) * D_HID + off;
      gl_lds16(hbre + ga, &Ar[buf][c * 8]);
      gl_lds16(hbim + ga, &Ai[buf][c * 8]);
      gl_lds16(wdrT + gb, &Brs[buf][c * 8]);
      gl_lds16(wdiT + gb, &Bis[buf][c * 8]);
    }
  };
  stage(0, 0);
  for (int t = 0; t < 16; ++t) {
    const int cur = t & 1;
    if (t < 15) {
      stage(cur ^ 1, (t + 1) * 64);
      VMCNT(8);
    } else {
      VMCNT(0);
    }
    BARRIER();
#pragma unroll
    for (int kh = 0; kh < 2; ++kh) {
      bf16x8 ar[2], ai[2], ain[2], br[2], bi[2];
#pragma unroll
      for (int mt = 0; mt < 2; ++mt) {
        int row = wm + mt * 16 + lcol;
        int aoff = kh * 2048 + row * 32 + SWZ(quad, row) * 8;
        ar[mt] = *(const bf16x8*)&Ar[cur][aoff];
        ai[mt] = *(const bf16x8*)&Ai[cur][aoff];
#pragma unroll
        for (int jj = 0; jj < 8; ++jj) ain[mt][jj] = ai[mt][jj] ^ (short)0x8000;
      }
#pragma unroll
      for (int nt = 0; nt < 2; ++nt) {
        int row = wn + nt * 16 + lcol;
        int boff = kh * 2048 + row * 32 + SWZ(quad, row) * 8;
        br[nt] = *(const bf16x8*)&Brs[cur][boff];
        bi[nt] = *(const bf16x8*)&Bis[cur][boff];
      }
#pragma unroll
      for (int mt = 0; mt < 2; ++mt)
#pragma unroll
        for (int nt = 0; nt < 2; ++nt) {
          accre[mt][nt] = MFMA16(ar[mt], br[nt], accre[mt][nt]);
          accre[mt][nt] = MFMA16(ain[mt], bi[nt], accre[mt][nt]);
          accim[mt][nt] = MFMA16(ar[mt], bi[nt], accim[mt][nt]);
          accim[mt][nt] = MFMA16(ai[mt], br[nt], accim[mt][nt]);
        }
    }
    if (t < 15) BARRIER();
  }
  // folded bias_red: bias per n-col (2 cols per lane)
  float bre[2], bim[2];
#pragma unroll
  for (int nt = 0; nt < 2; ++nt) {
    int n = n0 + wn + nt * 16 + lcol;
    float sr = 0.f, si = 0.f;
#pragma unroll
    for (int kc = 0; kc < 8; ++kc) {
      sr += bpartr[kc * D_OUT + n];
      si += bparti[kc * D_OUT + n];
    }
    float brd = ea_br[n] - eg_br[n];
    float bid = ea_bi[n] - eg_bi[n];
    bre[nt] = sr + brd - bid;
    bim[nt] = si + brd + bid;
  }
#pragma unroll
  for (int mt = 0; mt < 2; ++mt)
#pragma unroll
    for (int r = 0; r < 4; ++r) {
      int m = m0 + wm + mt * 16 + quad * 4 + r;
      float t = 0.f;
#pragma unroll
      for (int nt = 0; nt < 2; ++nt) {
        int n = n0 + wn + nt * 16 + lcol;
        float cre = accre[mt][nt][r] + bre[nt];
        float cim = accim[mt][nt][r] + bim[nt];
        t += cre * cre + cim * cim;
        ore[(size_t)m * D_OUT + n] = cre;
        oim[(size_t)m * D_OUT + n] = cim;
        gatesA[(size_t)m * 1536 + n] = f2bf(sqrtf(cre * cre + cim * cim));
        candAre[(size_t)m * 1536 + n] = f2bf(cre);
        candAim[(size_t)m * 1536 + n] = f2bf(cim);
      }
#pragma unroll
      for (int off = 1; off < 16; off <<= 1) t += __shfl_xor(t, off);
      if (lcol == 0) atomicAdd(&tens[m], t * (1.f / 512.f));
    }
}

// ---------------- MFMA GEMM 2: gates z+r FUSED (shared A), tile 128x64 (R2) ----
__global__ __launch_bounds__(256) void k_gates(
    const short* __restrict__ gatesA,
    const short* __restrict__ gzwT, const short* __restrict__ grwT,
    const float* __restrict__ gz_w, const float* __restrict__ gz_b,
    const float* __restrict__ gr_w, const float* __restrict__ gr_b,
    const float* __restrict__ tens,
    const float* __restrict__ h_re, const float* __restrict__ h_im,
    float* __restrict__ zbuf,
    short* __restrict__ candAre, short* __restrict__ candAim) {
  __shared__ short As[2][8192];
  __shared__ short Bz[2][4096];
  __shared__ short Br[2][4096];
  const int m0 = blockIdx.x * 128, n0 = blockIdx.y * 64;
  const int tid = threadIdx.x;
  const int wid = tid >> 6, lane = tid & 63;
  const int quad = lane >> 4, lcol = lane & 15;
  const int wm = (wid >> 1) * 64, wn = (wid & 1) * 32;
  f32x4 accz[4][2], accr[4][2];
#pragma unroll
  for (int mt = 0; mt < 4; ++mt)
#pragma unroll
    for (int nt = 0; nt < 2; ++nt) {
      accz[mt][nt] = (f32x4){0.f, 0.f, 0.f, 0.f};
      accr[mt][nt] = (f32x4){0.f, 0.f, 0.f, 0.f};
    }
  auto stage = [&](int buf, int k0) {
#pragma unroll
    for (int i = 0; i < 4; ++i) {
      int c = i * 256 + tid;  // 0..1023
      int kh = c >> 9, row = (c >> 2) & 127, kq = c & 3;
      gl_lds16(gatesA + (size_t)(m0 + row) * 1536 + k0 + kh * 32 + SWZ(kq, row) * 8,
               &As[buf][c * 8]);
    }
#pragma unroll
    for (int i = 0; i < 2; ++i) {
      int c = i * 256 + tid;  // 0..511
      int kh = c >> 8, row = (c >> 2) & 63, kq = c & 3;
      size_t g = (size_t)(n0 + row) * 1536 + k0 + kh * 32 + SWZ(kq, row) * 8;
      gl_lds16(gzwT + g, &Bz[buf][c * 8]);
      gl_lds16(grwT + g, &Br[buf][c * 8]);
    }
  };
  stage(0, 0);
  for (int t = 0; t < 24; ++t) {
    const int cur = t & 1;
    if (t < 23) {
      stage(cur ^ 1, (t + 1) * 64);
      VMCNT(8);
    } else {
      VMCNT(0);
    }
    BARRIER();
#pragma unroll
    for (int kh = 0; kh < 2; ++kh) {
      bf16x8 a[4], bz[2], br[2];
#pragma unroll
      for (int mt = 0; mt < 4; ++mt) {
        int row = wm + mt * 16 + lcol;
        a[mt] = *(const bf16x8*)&As[cur][kh * 4096 + row * 32 + SWZ(quad, row) * 8];
      }
#pragma unroll
      for (int nt = 0; nt < 2; ++nt) {
        int row = wn + nt * 16 + lcol;
        int boff = kh * 2048 + row * 32 + SWZ(quad, row) * 8;
        bz[nt] = *(const bf16x8*)&Bz[cur][boff];
        br[nt] = *(const bf16x8*)&Br[cur][boff];
      }
#pragma unroll
      for (int mt = 0; mt < 4; ++mt)
#pragma unroll
        for (int nt = 0; nt < 2; ++nt) {
          accz[mt][nt] = MFMA16(a[mt], bz[nt], accz[mt][nt]);
          accr[mt][nt] = MFMA16(a[mt], br[nt], accr[mt][nt]);
        }
    }
    if (t < 23) BARRIER();
  }
#pragma unroll
  for (int mt = 0; mt < 4; ++mt)
#pragma unroll
    for (int nt = 0; nt < 2; ++nt)
#pragma unroll
      for (int r = 0; r < 4; ++r) {
        int m = m0 + wm + mt * 16 + quad * 4 + r;
        int n = n0 + wn + nt * 16 + lcol;
        float tv = tens[m];
        float zp = accz[mt][nt][r] + gz_b[n] + tv * gz_w[(size_t)512 * D_HID + n];
        zbuf[(size_t)m * D_HID + n] = 1.f / (1.f + expf(-zp));
        float rp = accr[mt][nt][r] + gr_b[n] + tv * gr_w[(size_t)512 * D_HID + n];
        float rr = 1.f / (1.f + expf(-rp));
        candAre[(size_t)m * 1536 + 512 + n] = f2bf(rr * h_re[(size_t)m * D_HID + n]);
        candAim[(size_t)m * 1536 + 512 + n] = f2bf(rr * h_im[(size_t)m * D_HID + n]);
      }
}

// ---------------- MFMA GEMM 3: candidate + GRU blend, tile 128x128 (R2) --------
__global__ __launch_bounds__(512) void k_cand(
    const short* __restrict__ candAre, const short* __restrict__ candAim,
    const short* __restrict__ ghrwT, const short* __restrict__ ghiwT,
    const float* __restrict__ ghr_b, const float* __restrict__ ghi_b,
    const float* __restrict__ ghr_w,
    const float* __restrict__ tens, const float* __restrict__ zbuf,
    const float* __restrict__ h_re, const float* __restrict__ h_im,
    float* __restrict__ nhre, float* __restrict__ nhim) {
  __shared__ short As[2][8192];
  __shared__ short Bs[2][8192];
  const int is_re = (blockIdx.z == 0);
  const short* A = is_re ? candAre : candAim;
  const short* Bt = is_re ? ghrwT : ghiwT;
  const float* bias = is_re ? ghr_b : ghi_b;
  const float* h = is_re ? h_re : h_im;
  float* outp = is_re ? nhre : nhim;
  const int m0 = blockIdx.x * 128, n0 = blockIdx.y * 128;
  const int tid = threadIdx.x;
  const int wid = tid >> 6, lane = tid & 63;
  const int quad = lane >> 4, lcol = lane & 15;
  const int wm = (wid >> 2) * 64, wn = (wid & 3) * 32;
  f32x4 acc[4][2];
#pragma unroll
  for (int mt = 0; mt < 4; ++mt)
#pragma unroll
    for (int nt = 0; nt < 2; ++nt) acc[mt][nt] = (f32x4){0.f, 0.f, 0.f, 0.f};
  auto stage = [&](int buf, int k0) {
#pragma unroll
    for (int i = 0; i < 2; ++i) {
      int c = i * 512 + tid;  // 0..1023
      int kh = c >> 9, row = (c >> 2) & 127, kq = c & 3;
      size_t off = k0 + kh * 32 + SWZ(kq, row) * 8;
      gl_lds16(A + (size_t)(m0 + row) * 1536 + off, &As[buf][c * 8]);
      gl_lds16(Bt + (size_t)(n0 + row) * 1536 + off, &Bs[buf][c * 8]);
    }
  };
  stage(0, 0);
  for (int t = 0; t < 24; ++t) {
    const int cur = t & 1;
    if (t < 23) {
      stage(cur ^ 1, (t + 1) * 64);
      VMCNT(4);
    } else {
      VMCNT(0);
    }
    BARRIER();
#pragma unroll
    for (int kh = 0; kh < 2; ++kh) {
      bf16x8 a[4], b[2];
#pragma unroll
      for (int mt = 0; mt < 4; ++mt) {
        int row = wm + mt * 16 + lcol;
        a[mt] = *(const bf16x8*)&As[cur][kh * 4096 + row * 32 + SWZ(quad, row) * 8];
      }
#pragma unroll
      for (int nt = 0; nt < 2; ++nt) {
        int row = wn + nt * 16 + lcol;
        b[nt] = *(const bf16x8*)&Bs[cur][kh * 4096 + row * 32 + SWZ(quad, row) * 8];
      }
#pragma unroll
      for (int mt = 0; mt < 4; ++mt)
#pragma unroll
        for (int nt = 0; nt < 2; ++nt)
          acc[mt][nt] = MFMA16(a[mt], b[nt], acc[mt][nt]);
    }
    if (t < 23) BARRIER();
  }
#pragma unroll
  for (int mt = 0; mt < 4; ++mt)
#pragma unroll
    for (int nt = 0; nt < 2; ++nt)
#pragma unroll
      for (int r = 0; r < 4; ++r) {
        int m = m0 + wm + mt * 16 + quad * 4 + r;
        int n = n0 + wn + nt * 16 + lcol;
        float pre = acc[mt][nt][r] + bias[n];
        if (is_re) pre += tens[m] * ghr_w[(size_t)512 * D_HID + n];
        float cand = tanhf(pre);
        float z = zbuf[(size_t)m * D_HID + n];
        float hv = h[(size_t)m * D_HID + n];
        outp[(size_t)m * D_HID + n] = (1.f - z) * hv + z * cand;
      }
}

// ---------------- faction sync: two-stage ----------------
__global__ __launch_bounds__(256) void k_fsum_part(
    const float* __restrict__ nhre, const float* __restrict__ nhim,
    float* __restrict__ fpart) {
  int f = blockIdx.x >> 3, rc = blockIdx.x & 7, comp = blockIdx.y;
  const float* src = comp ? nhim : nhre;
  int row0 = f * 256 + rc * 32;
#pragma unroll
  for (int nc = 0; nc < 4; ++nc) {
    int n = nc * 256 + threadIdx.x;
    float s = 0.f;
    const float* base = src + (size_t)row0 * D_HID + n;
    for (int jj = 0; jj < 32; ++jj) s += base[(size_t)jj * D_HID];
    fpart[((size_t)comp * 64 + blockIdx.x) * D_HID + n] = s;
  }
}

__global__ __launch_bounds__(256) void k_fsum_red(
    const float* __restrict__ fpart,
    float* __restrict__ fsre, float* __restrict__ fsim,
    float* __restrict__ gre, float* __restrict__ gim) {
  int n = blockIdx.x * 256 + threadIdx.x;
  int comp = blockIdx.y;
  float* fs = comp ? fsim : fsre;
  float* g = comp ? gim : gre;
  float gsum = 0.f;
#pragma unroll
  for (int f = 0; f < 8; ++f) {
    float sf = 0.f;
#pragma unroll
    for (int rc = 0; rc < 8; ++rc)
      sf += fpart[((size_t)comp * 64 + f * 8 + rc) * D_HID + n];
    fs[f * D_HID + n] = sf;
    gsum += sf;
  }
  g[n] = gsum * (1.f / 2048.f);
}

__global__ __launch_bounds__(256) void k_sync(
    float* __restrict__ nhre, float* __restrict__ nhim,
    const float* __restrict__ fsre, const float* __restrict__ fsim,
    const float* __restrict__ gre, const float* __restrict__ gim,
    const int* __restrict__ step) {
  int idx = blockIdx.x * 256 + threadIdx.x;
  int m = idx >> 10, n = idx & 1023;
  int f = m >> 8;
  float vr = nhre[idx], vi = nhim[idx];
  vr = 0.85f * vr + 0.15f * (fsre[f * D_HID + n] * (1.f / 256.f));
  vi = 0.85f * vi + 0.15f * (fsim[f * D_HID + n] * (1.f / 256.f));
  if (step[0] > 5 && (m & 255) < 64) {
    vr = 0.85f * vr + 0.15f * gre[n];
    vi = 0.85f * vi + 0.15f * gim[n];
  }
  nhre[idx] = vr;
  nhim[idx] = vi;
}

// ---------------- combine stage1 with fused softmax stats ----------------
// Each block redundantly computes softmax stats over tens[2048] (trivial);
// block (0,0) additionally writes meanT. k_stats launch eliminated.
__global__ __launch_bounds__(256) void k_comb_part(
    const float* __restrict__ ore, const float* __restrict__ oim,
    const float* __restrict__ tens, float* __restrict__ cpart,
    float* __restrict__ meanT_out) {
  __shared__ float redv[4];
  __shared__ float s_max, s_inv;
  __shared__ float wl[128];
  int tid = threadIdx.x;
  int wid = tid >> 6, lane = tid & 63;
  float lv[8];
  float mx = -1e30f;
#pragma unroll
  for (int j2 = 0; j2 < 8; ++j2) {
    lv[j2] = tens[tid + j2 * 256];
    mx = fmaxf(mx, lv[j2]);
  }
  for (int off = 32; off; off >>= 1) mx = fmaxf(mx, __shfl_xor(mx, off));
  if (lane == 0) redv[wid] = mx;
  __syncthreads();
  if (tid == 0)
    s_max = fmaxf(fmaxf(redv[0], redv[1]), fmaxf(redv[2], redv[3]));
  __syncthreads();
  mx = s_max;
  float se = 0.f, st = 0.f;
#pragma unroll
  for (int j2 = 0; j2 < 8; ++j2) { se += expf(lv[j2] - mx); st += lv[j2]; }
  for (int off = 32; off; off >>= 1) se += __shfl_xor(se, off);
  if (lane == 0) redv[wid] = se;
  __syncthreads();
  if (tid == 0) s_inv = 1.f / (redv[0] + redv[1] + redv[2] + redv[3]);
  __syncthreads();
  if (blockIdx.x == 0 && blockIdx.y == 0) {
    for (int off = 32; off; off >>= 1) st += __shfl_xor(st, off);
    if (lane == 0) redv[wid] = st;
    __syncthreads();
    if (tid == 0)
      meanT_out[0] = (redv[0] + redv[1] + redv[2] + redv[3]) * (1.f / 2048.f);
  }
  int mc = blockIdx.y;
  if (tid < 128) wl[tid] = expf(tens[mc * 128 + tid] - mx) * s_inv;
  __syncthreads();
  int j = blockIdx.x * 256 + tid;
  const float* src = (j < 512) ? ore : oim;
  int col = j & 511;
  float s = 0.f;
  for (int i = 0; i < 128; ++i) {
    int m = mc * 128 + i;
    s += wl[i] * src[(size_t)m * D_OUT + col];
  }
  cpart[(size_t)mc * 1024 + j] = s;
}

// ---------------- pred stage1 (comb reduction fused in) ----------------
__global__ __launch_bounds__(256) void k_pred_part(
    const float* __restrict__ cpart, const float* __restrict__ oh_w,
    float* __restrict__ ppart) {
  __shared__ float combs[128];
  int tid = threadIdx.x;
  int jc = blockIdx.y;
  if (tid < 128) {
    float s = 0.f;
#pragma unroll
    for (int mc = 0; mc < 16; ++mc) s += cpart[(size_t)mc * 1024 + jc * 128 + tid];
    combs[tid] = s;
  }
  __syncthreads();
  int n = blockIdx.x * 256 + tid;
  float s = 0.f;
#pragma unroll 8
  for (int i = 0; i < 128; ++i)
    s += combs[i] * oh_w[(size_t)(jc * 128 + i) * D_IN + n];
  ppart[(size_t)jc * D_IN + n] = s;
}

__global__ __launch_bounds__(256) void k_pred_red(
    const float* __restrict__ ppart, const float* __restrict__ oh_b,
    float* __restrict__ pred) {
  int n = blockIdx.x * 256 + threadIdx.x;
  float s = oh_b[n];
#pragma unroll
  for (int jc = 0; jc < 8; ++jc) s += ppart[(size_t)jc * D_IN + n];
  pred[n] = s;
}

// ---------------- launcher ----------------
extern "C" void kernel_launch(void* const* d_in, const int* in_sizes, int n_in,
                              void* d_out, int out_size, void* d_ws, size_t ws_size,
                              hipStream_t stream) {
  const float* x     = (const float*)d_in[0];
  const float* h_re  = (const float*)d_in[1];
  const float* h_im  = (const float*)d_in[2];
  const float* ea_wr = (const float*)d_in[3];
  const float* ea_br = (const float*)d_in[4];
  const float* ea_wi = (const float*)d_in[5];
  const float* ea_bi = (const float*)d_in[6];
  const float* eg_wr = (const float*)d_in[7];
  const float* eg_br = (const float*)d_in[8];
  const float* eg_wi = (const float*)d_in[9];
  const float* eg_bi = (const float*)d_in[10];
  const float* gz_w  = (const float*)d_in[11];
  const float* gz_b  = (const float*)d_in[12];
  const float* gr_w  = (const float*)d_in[13];
  const float* gr_b  = (const float*)d_in[14];
  const float* ghr_w = (const float*)d_in[15];
  const float* ghr_b = (const float*)d_in[16];
  const float* ghi_w = (const float*)d_in[17];
  const float* ghi_b = (const float*)d_in[18];
  const float* oh_w  = (const float*)d_in[19];
  const float* oh_b  = (const float*)d_in[20];
  const int*   step  = (const int*)d_in[21];

  float* out = (float*)d_out;
  float* pred_out  = out;
  float* meanT_out = out + 512;
  float* nhre_out  = out + 513;
  float* nhim_out  = out + 513 + N_CELLS * D_HID;

  char* p = (char*)d_ws;
  auto carve = [&](size_t bytes) { char* r = p; p += (bytes + 255) & ~(size_t)255; return r; };
  short* wdrT   = (short*)carve(512 * 1024 * 2);
  short* wdiT   = (short*)carve(512 * 1024 * 2);
  short* gzwT   = (short*)carve(1024 * 1536 * 2);
  short* grwT   = (short*)carve(1024 * 1536 * 2);
  short* ghrwT  = (short*)carve(1024 * 1536 * 2);
  short* ghiwT  = (short*)carve(1024 * 1536 * 2);
  short* hbre   = (short*)carve(2048 * 1024 * 2);
  short* hbim   = (short*)carve(2048 * 1024 * 2);
  short* gatesA = (short*)carve((size_t)2048 * 1536 * 2);
  short* candAre= (short*)carve((size_t)2048 * 1536 * 2);
  short* candAim= (short*)carve((size_t)2048 * 1536 * 2);
  float* ore    = (float*)carve(2048 * 512 * 4);
  float* oim    = (float*)carve(2048 * 512 * 4);
  float* zbuf   = (float*)carve((size_t)2048 * 1024 * 4);
  float* bpartr = (float*)carve(8 * 512 * 4);
  float* bparti = (float*)carve(8 * 512 * 4);
  float* tens   = (float*)carve(2048 * 4);
  float* fpart  = (float*)carve(2 * 64 * 1024 * 4);
  float* fsre   = (float*)carve(8 * 1024 * 4);
  float* fsim   = (float*)carve(8 * 1024 * 4);
  float* gre    = (float*)carve(1024 * 4);
  float* gim    = (float*)carve(1024 * 4);
  float* cpart  = (float*)carve(16 * 1024 * 4);
  float* ppart  = (float*)carve(8 * 512 * 4);

  hipLaunchKernelGGL(k_transpose_all, dim3(48, 32, 5), dim3(256), 0, stream,
                     gz_w, gr_w, ghr_w, ghi_w, gzwT, grwT, ghrwT, ghiwT,
                     ea_wr, eg_wr, ea_wi, eg_wi, wdrT, wdiT);
  hipLaunchKernelGGL(k_prep_h, dim3(2048), dim3(256), 0, stream,
                     h_re, h_im, hbre, hbim, gatesA, tens);
  hipLaunchKernelGGL(k_bias_part, dim3(2, 8), dim3(256), 0, stream,
                     x, ea_wr, ea_wi, eg_wr, eg_wi, bpartr, bparti);
  hipLaunchKernelGGL(k_engine, dim3(32, 8), dim3(256), 0, stream,
                     hbre, hbim, wdrT, wdiT, bpartr, bparti,
                     ea_br, ea_bi, eg_br, eg_bi,
                     ore, oim, gatesA, candAre, candAim, tens);
  hipLaunchKernelGGL(k_gates, dim3(16, 16), dim3(256), 0, stream,
                     gatesA, gzwT, grwT, gz_w, gz_b, gr_w, gr_b, tens,
                     h_re, h_im, zbuf, candAre, candAim);
  hipLaunchKernelGGL(k_cand, dim3(16, 8, 2), dim3(512), 0, stream,
                     candAre, candAim, ghrwT, ghiwT, ghr_b, ghi_b, ghr_w,
                     tens, zbuf, h_re, h_im, nhre_out, nhim_out);
  hipLaunchKernelGGL(k_fsum_part, dim3(64, 2), dim3(256), 0, stream,
                     nhre_out, nhim_out, fpart);
  hipLaunchKernelGGL(k_fsum_red, dim3(4, 2), dim3(256), 0, stream,
                     fpart, fsre, fsim, gre, gim);
  hipLaunchKernelGGL(k_sync, dim3((N_CELLS * D_HID) / 256), dim3(256), 0, stream,
                     nhre_out, nhim_out, fsre, fsim, gre, gim, step);
  hipLaunchKernelGGL(k_comb_part, dim3(4, 16), dim3(256), 0, stream,
                     ore, oim, tens, cpart, meanT_out);
  hipLaunchKernelGGL(k_pred_part, dim3(2, 8), dim3(256), 0, stream, cpart, oh_w, ppart);
  hipLaunchKernelGGL(k_pred_red, dim3(2), dim3(256), 0, stream, ppart, oh_b, pred_out);
}

// Round 10
// 290.254 us; speedup vs baseline: 1.1098x; 1.0094x over previous
//
#include <hip/hip_runtime.h>
#include <math.h>

#define N_CELLS 2048
#define D_IN 512
#define D_HID 1024
#define D_OUT 512

typedef __attribute__((ext_vector_type(8))) short bf16x8;
typedef __attribute__((ext_vector_type(4))) float f32x4;
typedef __attribute__((ext_vector_type(4))) short short4v;

#define MFMA16(a, b, c) __builtin_amdgcn_mfma_f32_16x16x32_bf16(a, b, c, 0, 0, 0)

__device__ __forceinline__ short f2bf(float f) {
  union { float f; unsigned u; } v; v.f = f;
  unsigned r = (v.u + 0x7FFFu + ((v.u >> 16) & 1u)) >> 16;
  return (short)r;
}

__device__ __forceinline__ void gl_lds16(const void* g, void* l) {
  __builtin_amdgcn_global_load_lds(
      (const __attribute__((address_space(1))) void*)g,
      (__attribute__((address_space(3))) void*)l, 16, 0, 0);
}

#define VMCNT(n) asm volatile("s_waitcnt vmcnt(" #n ")" ::: "memory")
#define BARRIER() asm volatile("s_barrier" ::: "memory")

// LDS bank-conflict swizzle (proven 0-conflict in R6): slot' = slot ^ ((row>>1)&3)
// applied on global SOURCE of global_load_lds (dest linear) and on ds_read slot.
#define SWZ(kq, row) ((kq) ^ (((row) >> 1) & 3))

// ---------------- prep: all weight transposes, vectorized stores ----------------
__global__ __launch_bounds__(256) void k_transpose_all(
    const float* __restrict__ w0, const float* __restrict__ w1,
    const float* __restrict__ w2, const float* __restrict__ w3,
    short* __restrict__ t0, short* __restrict__ t1,
    short* __restrict__ t2, short* __restrict__ t3,
    const float* __restrict__ ea_wr, const float* __restrict__ eg_wr,
    const float* __restrict__ ea_wi, const float* __restrict__ eg_wi,
    short* __restrict__ wdrT, short* __restrict__ wdiT) {
  const int k0 = blockIdx.x * 32, n0 = blockIdx.y * 32;
  const int c = threadIdx.x & 31, r4 = threadIdx.x >> 5;
  const int nl = threadIdx.x >> 3, kq = threadIdx.x & 7;
  if (blockIdx.z < 4) {
    const float* w = (blockIdx.z == 0) ? w0 : (blockIdx.z == 1) ? w1
                   : (blockIdx.z == 2) ? w2 : w3;
    short* wT = (blockIdx.z == 0) ? t0 : (blockIdx.z == 1) ? t1
              : (blockIdx.z == 2) ? t2 : t3;
    __shared__ float t[32][33];
#pragma unroll
    for (int i = 0; i < 4; ++i) {
      int kl = r4 * 4 + i;
      int k = k0 + kl;
      int srcrow = (k < 512) ? k : k + 1;
      t[kl][c] = w[(size_t)srcrow * D_HID + n0 + c];
    }
    __syncthreads();
    short4v v;
#pragma unroll
    for (int jv = 0; jv < 4; ++jv) v[jv] = f2bf(t[kq * 4 + jv][nl]);
    *(short4v*)&wT[(size_t)(n0 + nl) * 1536 + k0 + kq * 4] = v;
  } else {
    if (blockIdx.x >= 32 || blockIdx.y >= 16) return;
    __shared__ float tr[32][33], ti[32][33];
#pragma unroll
    for (int i = 0; i < 4; ++i) {
      int kl = r4 * 4 + i;
      int src = (512 + k0 + kl) * D_OUT + n0 + c;
      tr[kl][c] = ea_wr[src] - eg_wr[src];
      ti[kl][c] = ea_wi[src] - eg_wi[src];
    }
    __syncthreads();
    short4v vr, vi;
#pragma unroll
    for (int jv = 0; jv < 4; ++jv) {
      vr[jv] = f2bf(tr[kq * 4 + jv][nl]);
      vi[jv] = f2bf(ti[kq * 4 + jv][nl]);
    }
    size_t dst = (size_t)(n0 + nl) * D_HID + k0 + kq * 4;
    *(short4v*)&wdrT[dst] = vr;
    *(short4v*)&wdiT[dst] = vi;
  }
}

// h fp32 -> bf16 + |h| into gatesA cols 512..1535 ; also zero tens
__global__ __launch_bounds__(256) void k_prep_h(
    const float* __restrict__ h_re, const float* __restrict__ h_im,
    short* __restrict__ hbre, short* __restrict__ hbim, short* __restrict__ gatesA,
    float* __restrict__ tens) {
  if (threadIdx.x == 0) tens[blockIdx.x] = 0.f;
  int idx4 = (blockIdx.x * 256 + threadIdx.x) * 4;
  int m = idx4 >> 10, n = idx4 & 1023;
  float4 hr = *(const float4*)&h_re[idx4];
  float4 hi = *(const float4*)&h_im[idx4];
  short4v br, bi, bm;
  br.x = f2bf(hr.x); br.y = f2bf(hr.y); br.z = f2bf(hr.z); br.w = f2bf(hr.w);
  bi.x = f2bf(hi.x); bi.y = f2bf(hi.y); bi.z = f2bf(hi.z); bi.w = f2bf(hi.w);
  bm.x = f2bf(sqrtf(hr.x * hr.x + hi.x * hi.x));
  bm.y = f2bf(sqrtf(hr.y * hr.y + hi.y * hi.y));
  bm.z = f2bf(sqrtf(hr.z * hr.z + hi.z * hi.z));
  bm.w = f2bf(sqrtf(hr.w * hr.w + hi.w * hi.w));
  *(short4v*)&hbre[idx4] = br;
  *(short4v*)&hbim[idx4] = bi;
  *(short4v*)&gatesA[(size_t)m * 1536 + 512 + n] = bm;
}

// ---------------- bias from x: split-K stage 1 (reduce folded into k_engine) ----
__global__ __launch_bounds__(256) void k_bias_part(
    const float* __restrict__ x,
    const float* __restrict__ ea_wr, const float* __restrict__ ea_wi,
    const float* __restrict__ eg_wr, const float* __restrict__ eg_wi,
    float* __restrict__ bpartr, float* __restrict__ bparti) {
  int n = blockIdx.x * 256 + threadIdx.x;
  int kc = blockIdx.y;
  float sr = 0.f, si = 0.f;
  for (int i = 0; i < 64; ++i) {
    int k = kc * 64 + i;
    float xv = x[k];
    int idx = k * D_OUT + n;
    sr += xv * (ea_wr[idx] - eg_wr[idx]);
    si += xv * (ea_wi[idx] - eg_wi[idx]);
  }
  bpartr[kc * D_OUT + n] = sr;
  bparti[kc * D_OUT + n] = si;
}

// ---------------- MFMA GEMM 1: complex engine, tile 64x64, BK=64 (unchanged) ----
__global__ __launch_bounds__(256) void k_engine(
    const short* __restrict__ hbre, const short* __restrict__ hbim,
    const short* __restrict__ wdrT, const short* __restrict__ wdiT,
    const float* __restrict__ bpartr, const float* __restrict__ bparti,
    const float* __restrict__ ea_br, const float* __restrict__ ea_bi,
    const float* __restrict__ eg_br, const float* __restrict__ eg_bi,
    float* __restrict__ ore, float* __restrict__ oim,
    short* __restrict__ gatesA, short* __restrict__ candAre, short* __restrict__ candAim,
    float* __restrict__ tens) {
  __shared__ short Ar[2][4096], Ai[2][4096];
  __shared__ short Brs[2][4096], Bis[2][4096];
  const int m0 = blockIdx.x * 64, n0 = blockIdx.y * 64;
  const int tid = threadIdx.x;
  const int wid = tid >> 6, lane = tid & 63;
  const int quad = lane >> 4, lcol = lane & 15;
  const int wm = (wid >> 1) * 32, wn = (wid & 1) * 32;
  f32x4 accre[2][2], accim[2][2];
#pragma unroll
  for (int mt = 0; mt < 2; ++mt)
#pragma unroll
    for (int nt = 0; nt < 2; ++nt) {
      accre[mt][nt] = (f32x4){0.f, 0.f, 0.f, 0.f};
      accim[mt][nt] = (f32x4){0.f, 0.f, 0.f, 0.f};
    }
  auto stage = [&](int buf, int k0) {
#pragma unroll
    for (int i = 0; i < 2; ++i) {
      int c = i * 256 + tid;  // 0..511
      int kh = c >> 8, row = (c >> 2) & 63, kq = c & 3;
      size_t off = k0 + kh * 32 + SWZ(kq, row) * 8;
      size_t ga = (size_t)(m0 + row) * D_HID + off;
      size_t gb = (size_t)(n0 + row) * D_HID + off;
      gl_lds16(hbre + ga, &Ar[buf][c * 8]);
      gl_lds16(hbim + ga, &Ai[buf][c * 8]);
      gl_lds16(wdrT + gb, &Brs[buf][c * 8]);
      gl_lds16(wdiT + gb, &Bis[buf][c * 8]);
    }
  };
  stage(0, 0);
  for (int t = 0; t < 16; ++t) {
    const int cur = t & 1;
    if (t < 15) {
      stage(cur ^ 1, (t + 1) * 64);
      VMCNT(8);
    } else {
      VMCNT(0);
    }
    BARRIER();
#pragma unroll
    for (int kh = 0; kh < 2; ++kh) {
      bf16x8 ar[2], ai[2], ain[2], br[2], bi[2];
#pragma unroll
      for (int mt = 0; mt < 2; ++mt) {
        int row = wm + mt * 16 + lcol;
        int aoff = kh * 2048 + row * 32 + SWZ(quad, row) * 8;
        ar[mt] = *(const bf16x8*)&Ar[cur][aoff];
        ai[mt] = *(const bf16x8*)&Ai[cur][aoff];
#pragma unroll
        for (int jj = 0; jj < 8; ++jj) ain[mt][jj] = ai[mt][jj] ^ (short)0x8000;
      }
#pragma unroll
      for (int nt = 0; nt < 2; ++nt) {
        int row = wn + nt * 16 + lcol;
        int boff = kh * 2048 + row * 32 + SWZ(quad, row) * 8;
        br[nt] = *(const bf16x8*)&Brs[cur][boff];
        bi[nt] = *(const bf16x8*)&Bis[cur][boff];
      }
#pragma unroll
      for (int mt = 0; mt < 2; ++mt)
#pragma unroll
        for (int nt = 0; nt < 2; ++nt) {
          accre[mt][nt] = MFMA16(ar[mt], br[nt], accre[mt][nt]);
          accre[mt][nt] = MFMA16(ain[mt], bi[nt], accre[mt][nt]);
          accim[mt][nt] = MFMA16(ar[mt], bi[nt], accim[mt][nt]);
          accim[mt][nt] = MFMA16(ai[mt], br[nt], accim[mt][nt]);
        }
    }
    if (t < 15) BARRIER();
  }
  float bre[2], bim[2];
#pragma unroll
  for (int nt = 0; nt < 2; ++nt) {
    int n = n0 + wn + nt * 16 + lcol;
    float sr = 0.f, si = 0.f;
#pragma unroll
    for (int kc = 0; kc < 8; ++kc) {
      sr += bpartr[kc * D_OUT + n];
      si += bparti[kc * D_OUT + n];
    }
    float brd = ea_br[n] - eg_br[n];
    float bid = ea_bi[n] - eg_bi[n];
    bre[nt] = sr + brd - bid;
    bim[nt] = si + brd + bid;
  }
#pragma unroll
  for (int mt = 0; mt < 2; ++mt)
#pragma unroll
    for (int r = 0; r < 4; ++r) {
      int m = m0 + wm + mt * 16 + quad * 4 + r;
      float t = 0.f;
#pragma unroll
      for (int nt = 0; nt < 2; ++nt) {
        int n = n0 + wn + nt * 16 + lcol;
        float cre = accre[mt][nt][r] + bre[nt];
        float cim = accim[mt][nt][r] + bim[nt];
        t += cre * cre + cim * cim;
        ore[(size_t)m * D_OUT + n] = cre;
        oim[(size_t)m * D_OUT + n] = cim;
        gatesA[(size_t)m * 1536 + n] = f2bf(sqrtf(cre * cre + cim * cim));
        candAre[(size_t)m * 1536 + n] = f2bf(cre);
        candAim[(size_t)m * 1536 + n] = f2bf(cim);
      }
#pragma unroll
      for (int off = 1; off < 16; off <<= 1) t += __shfl_xor(t, off);
      if (lcol == 0) atomicAdd(&tens[m], t * (1.f / 512.f));
    }
}

// ---------------- MFMA GEMM 2: gates z+r FUSED, tile 128x64, SPLIT-K=2 --------
// 512 thr / 8 waves: waves 0-3 compute K[0,768), waves 4-7 K[768,1536) in
// parallel -> 12-iter chain instead of 24. Cross-half reduce via LDS (reuses
// As). grid (16,16)=256 blocks = 1/CU, LDS 128KB.
__global__ __launch_bounds__(512) void k_gates(
    const short* __restrict__ gatesA,
    const short* __restrict__ gzwT, const short* __restrict__ grwT,
    const float* __restrict__ gz_w, const float* __restrict__ gz_b,
    const float* __restrict__ gr_w, const float* __restrict__ gr_b,
    const float* __restrict__ tens,
    const float* __restrict__ h_re, const float* __restrict__ h_im,
    float* __restrict__ zbuf,
    short* __restrict__ candAre, short* __restrict__ candAim) {
  __shared__ short As[2][2][8192];   // [buf][kg][128 rows x 64 k] 64KB
  __shared__ short Bzs[2][2][4096];  // [buf][kg][64 x 64] 32KB
  __shared__ short Brs[2][2][4096];  // 32KB
  const int m0 = blockIdx.x * 128, n0 = blockIdx.y * 64;
  const int tid = threadIdx.x;
  const int wid = tid >> 6, lane = tid & 63;
  const int quad = lane >> 4, lcol = lane & 15;
  const int kg = wid >> 2, ws = wid & 3;
  const int wm = (ws >> 1) * 64, wn = (ws & 1) * 32;
  f32x4 accz[4][2], accr[4][2];
#pragma unroll
  for (int mt = 0; mt < 4; ++mt)
#pragma unroll
    for (int nt = 0; nt < 2; ++nt) {
      accz[mt][nt] = (f32x4){0.f, 0.f, 0.f, 0.f};
      accr[mt][nt] = (f32x4){0.f, 0.f, 0.f, 0.f};
    }
  auto stage = [&](int buf, int t) {
#pragma unroll
    for (int i = 0; i < 4; ++i) {
      int c = i * 512 + tid;  // 0..2047 A chunks (1024 per K-half)
      int kgs = c >> 10, rem = c & 1023;
      int kh = rem >> 9, row = (rem >> 2) & 127, kq = rem & 3;
      gl_lds16(gatesA + (size_t)(m0 + row) * 1536 + kgs * 768 + t * 64 +
                   kh * 32 + SWZ(kq, row) * 8,
               &As[buf][kgs][rem * 8]);
    }
#pragma unroll
    for (int i = 0; i < 4; ++i) {
      int j = i * 512 + tid;  // 0..2047 B chunks (Bz:1024, Br:1024)
      int bsel = j >> 10, rem = j & 1023;
      int kgs = rem >> 9, r2 = rem & 511;
      int kh = r2 >> 8, row = (r2 >> 2) & 63, kq = r2 & 3;
      size_t g = (size_t)(n0 + row) * 1536 + kgs * 768 + t * 64 +
                 kh * 32 + SWZ(kq, row) * 8;
      if (bsel == 0) gl_lds16(gzwT + g, &Bzs[buf][kgs][r2 * 8]);
      else           gl_lds16(grwT + g, &Brs[buf][kgs][r2 * 8]);
    }
  };
  stage(0, 0);
  for (int t = 0; t < 12; ++t) {
    const int cur = t & 1;
    if (t < 11) {
      stage(cur ^ 1, t + 1);
      VMCNT(8);
    } else {
      VMCNT(0);
    }
    BARRIER();
#pragma unroll
    for (int kh = 0; kh < 2; ++kh) {
      bf16x8 a[4], bz[2], br[2];
#pragma unroll
      for (int mt = 0; mt < 4; ++mt) {
        int row = wm + mt * 16 + lcol;
        a[mt] = *(const bf16x8*)&As[cur][kg][kh * 4096 + row * 32 + SWZ(quad, row) * 8];
      }
#pragma unroll
      for (int nt = 0; nt < 2; ++nt) {
        int row = wn + nt * 16 + lcol;
        int boff = kh * 2048 + row * 32 + SWZ(quad, row) * 8;
        bz[nt] = *(const bf16x8*)&Bzs[cur][kg][boff];
        br[nt] = *(const bf16x8*)&Brs[cur][kg][boff];
      }
#pragma unroll
      for (int mt = 0; mt < 4; ++mt)
#pragma unroll
        for (int nt = 0; nt < 2; ++nt) {
          accz[mt][nt] = MFMA16(a[mt], bz[nt], accz[mt][nt]);
          accr[mt][nt] = MFMA16(a[mt], br[nt], accr[mt][nt]);
        }
    }
    if (t < 11) BARRIER();
  }
  // cross-half reduction via LDS (reuse As: 64KB = 16384 floats)
  float* red = (float*)&As[0][0][0];
  const int rbase = ws * 4096;  // per-ws region: z 2048 + r 2048 floats
  BARRIER();
  if (kg == 1) {
#pragma unroll
    for (int mt = 0; mt < 4; ++mt)
#pragma unroll
      for (int nt = 0; nt < 2; ++nt)
#pragma unroll
        for (int r = 0; r < 4; ++r) {
          int idx = rbase + ((mt * 2 + nt) * 4 + r) * 64 + lane;
          red[idx] = accz[mt][nt][r];
          red[idx + 2048] = accr[mt][nt][r];
        }
  }
  BARRIER();
  if (kg == 0) {
#pragma unroll
    for (int mt = 0; mt < 4; ++mt)
#pragma unroll
      for (int nt = 0; nt < 2; ++nt)
#pragma unroll
        for (int r = 0; r < 4; ++r) {
          int idx = rbase + ((mt * 2 + nt) * 4 + r) * 64 + lane;
          int m = m0 + wm + mt * 16 + quad * 4 + r;
          int n = n0 + wn + nt * 16 + lcol;
          float tv = tens[m];
          float zp = accz[mt][nt][r] + red[idx] + gz_b[n] +
                     tv * gz_w[(size_t)512 * D_HID + n];
          zbuf[(size_t)m * D_HID + n] = 1.f / (1.f + expf(-zp));
          float rp = accr[mt][nt][r] + red[idx + 2048] + gr_b[n] +
                     tv * gr_w[(size_t)512 * D_HID + n];
          float rr = 1.f / (1.f + expf(-rp));
          candAre[(size_t)m * 1536 + 512 + n] = f2bf(rr * h_re[(size_t)m * D_HID + n]);
          candAim[(size_t)m * 1536 + 512 + n] = f2bf(rr * h_im[(size_t)m * D_HID + n]);
        }
  }
}

// ---------------- MFMA GEMM 3: candidate + GRU blend, 128x128, SPLIT-K=2 ------
// 512 thr / 8 waves: K-halves in parallel, 12-iter chain. grid (16,8,2)=256.
__global__ __launch_bounds__(512) void k_cand(
    const short* __restrict__ candAre, const short* __restrict__ candAim,
    const short* __restrict__ ghrwT, const short* __restrict__ ghiwT,
    const float* __restrict__ ghr_b, const float* __restrict__ ghi_b,
    const float* __restrict__ ghr_w,
    const float* __restrict__ tens, const float* __restrict__ zbuf,
    const float* __restrict__ h_re, const float* __restrict__ h_im,
    float* __restrict__ nhre, float* __restrict__ nhim) {
  __shared__ short As[2][2][8192];  // [buf][kg][128 x 64] 64KB
  __shared__ short Bs[2][2][8192];  // [buf][kg][128 x 64] 64KB
  const int is_re = (blockIdx.z == 0);
  const short* A = is_re ? candAre : candAim;
  const short* Bt = is_re ? ghrwT : ghiwT;
  const float* bias = is_re ? ghr_b : ghi_b;
  const float* h = is_re ? h_re : h_im;
  float* outp = is_re ? nhre : nhim;
  const int m0 = blockIdx.x * 128, n0 = blockIdx.y * 128;
  const int tid = threadIdx.x;
  const int wid = tid >> 6, lane = tid & 63;
  const int quad = lane >> 4, lcol = lane & 15;
  const int kg = wid >> 2, ws = wid & 3;
  const int wm = (ws >> 1) * 64, wn = (ws & 1) * 64;
  f32x4 acc[4][4];
#pragma unroll
  for (int mt = 0; mt < 4; ++mt)
#pragma unroll
    for (int nt = 0; nt < 4; ++nt) acc[mt][nt] = (f32x4){0.f, 0.f, 0.f, 0.f};
  auto stage = [&](int buf, int t) {
#pragma unroll
    for (int i = 0; i < 4; ++i) {
      int c = i * 512 + tid;  // 0..2047 A chunks
      int kgs = c >> 10, rem = c & 1023;
      int kh = rem >> 9, row = (rem >> 2) & 127, kq = rem & 3;
      gl_lds16(A + (size_t)(m0 + row) * 1536 + kgs * 768 + t * 64 +
                   kh * 32 + SWZ(kq, row) * 8,
               &As[buf][kgs][rem * 8]);
    }
#pragma unroll
    for (int i = 0; i < 4; ++i) {
      int j = i * 512 + tid;  // 0..2047 B chunks
      int kgs = j >> 10, rem = j & 1023;
      int kh = rem >> 9, row = (rem >> 2) & 127, kq = rem & 3;
      gl_lds16(Bt + (size_t)(n0 + row) * 1536 + kgs * 768 + t * 64 +
                   kh * 32 + SWZ(kq, row) * 8,
               &Bs[buf][kgs][rem * 8]);
    }
  };
  stage(0, 0);
  for (int t = 0; t < 12; ++t) {
    const int cur = t & 1;
    if (t < 11) {
      stage(cur ^ 1, t + 1);
      VMCNT(8);
    } else {
      VMCNT(0);
    }
    BARRIER();
#pragma unroll
    for (int kh = 0; kh < 2; ++kh) {
      bf16x8 a[4], b[4];
#pragma unroll
      for (int mt = 0; mt < 4; ++mt) {
        int row = wm + mt * 16 + lcol;
        a[mt] = *(const bf16x8*)&As[cur][kg][kh * 4096 + row * 32 + SWZ(quad, row) * 8];
      }
#pragma unroll
      for (int nt = 0; nt < 4; ++nt) {
        int row = wn + nt * 16 + lcol;
        b[nt] = *(const bf16x8*)&Bs[cur][kg][kh * 4096 + row * 32 + SWZ(quad, row) * 8];
      }
#pragma unroll
      for (int mt = 0; mt < 4; ++mt)
#pragma unroll
        for (int nt = 0; nt < 4; ++nt)
          acc[mt][nt] = MFMA16(a[mt], b[nt], acc[mt][nt]);
    }
    if (t < 11) BARRIER();
  }
  // cross-half reduction via LDS (reuse As: 64KB = 16384 floats)
  float* red = (float*)&As[0][0][0];
  const int rbase = ws * 4096;  // 4096 floats per ws region
  BARRIER();
  if (kg == 1) {
#pragma unroll
    for (int mt = 0; mt < 4; ++mt)
#pragma unroll
      for (int nt = 0; nt < 4; ++nt)
#pragma unroll
        for (int r = 0; r < 4; ++r)
          red[rbase + ((mt * 4 + nt) * 4 + r) * 64 + lane] = acc[mt][nt][r];
  }
  BARRIER();
  if (kg == 0) {
#pragma unroll
    for (int mt = 0; mt < 4; ++mt)
#pragma unroll
      for (int nt = 0; nt < 4; ++nt)
#pragma unroll
        for (int r = 0; r < 4; ++r) {
          int m = m0 + wm + mt * 16 + quad * 4 + r;
          int n = n0 + wn + nt * 16 + lcol;
          float pre = acc[mt][nt][r] +
                      red[rbase + ((mt * 4 + nt) * 4 + r) * 64 + lane] + bias[n];
          if (is_re) pre += tens[m] * ghr_w[(size_t)512 * D_HID + n];
          float cand = tanhf(pre);
          float z = zbuf[(size_t)m * D_HID + n];
          float hv = h[(size_t)m * D_HID + n];
          outp[(size_t)m * D_HID + n] = (1.f - z) * hv + z * cand;
        }
  }
}

// ---------------- faction sync: two-stage ----------------
__global__ __launch_bounds__(256) void k_fsum_part(
    const float* __restrict__ nhre, const float* __restrict__ nhim,
    float* __restrict__ fpart) {
  int f = blockIdx.x >> 3, rc = blockIdx.x & 7, comp = blockIdx.y;
  const float* src = comp ? nhim : nhre;
  int row0 = f * 256 + rc * 32;
#pragma unroll
  for (int nc = 0; nc < 4; ++nc) {
    int n = nc * 256 + threadIdx.x;
    float s = 0.f;
    const float* base = src + (size_t)row0 * D_HID + n;
    for (int jj = 0; jj < 32; ++jj) s += base[(size_t)jj * D_HID];
    fpart[((size_t)comp * 64 + blockIdx.x) * D_HID + n] = s;
  }
}

__global__ __launch_bounds__(256) void k_fsum_red(
    const float* __restrict__ fpart,
    float* __restrict__ fsre, float* __restrict__ fsim,
    float* __restrict__ gre, float* __restrict__ gim) {
  int n = blockIdx.x * 256 + threadIdx.x;
  int comp = blockIdx.y;
  float* fs = comp ? fsim : fsre;
  float* g = comp ? gim : gre;
  float gsum = 0.f;
#pragma unroll
  for (int f = 0; f < 8; ++f) {
    float sf = 0.f;
#pragma unroll
    for (int rc = 0; rc < 8; ++rc)
      sf += fpart[((size_t)comp * 64 + f * 8 + rc) * D_HID + n];
    fs[f * D_HID + n] = sf;
    gsum += sf;
  }
  g[n] = gsum * (1.f / 2048.f);
}

__global__ __launch_bounds__(256) void k_sync(
    float* __restrict__ nhre, float* __restrict__ nhim,
    const float* __restrict__ fsre, const float* __restrict__ fsim,
    const float* __restrict__ gre, const float* __restrict__ gim,
    const int* __restrict__ step) {
  int idx = blockIdx.x * 256 + threadIdx.x;
  int m = idx >> 10, n = idx & 1023;
  int f = m >> 8;
  float vr = nhre[idx], vi = nhim[idx];
  vr = 0.85f * vr + 0.15f * (fsre[f * D_HID + n] * (1.f / 256.f));
  vi = 0.85f * vi + 0.15f * (fsim[f * D_HID + n] * (1.f / 256.f));
  if (step[0] > 5 && (m & 255) < 64) {
    vr = 0.85f * vr + 0.15f * gre[n];
    vi = 0.85f * vi + 0.15f * gim[n];
  }
  nhre[idx] = vr;
  nhim[idx] = vi;
}

// ---------------- combine stage1 with fused softmax stats ----------------
__global__ __launch_bounds__(256) void k_comb_part(
    const float* __restrict__ ore, const float* __restrict__ oim,
    const float* __restrict__ tens, float* __restrict__ cpart,
    float* __restrict__ meanT_out) {
  __shared__ float redv[4];
  __shared__ float s_max, s_inv;
  __shared__ float wl[128];
  int tid = threadIdx.x;
  int wid = tid >> 6, lane = tid & 63;
  float lv[8];
  float mx = -1e30f;
#pragma unroll
  for (int j2 = 0; j2 < 8; ++j2) {
    lv[j2] = tens[tid + j2 * 256];
    mx = fmaxf(mx, lv[j2]);
  }
  for (int off = 32; off; off >>= 1) mx = fmaxf(mx, __shfl_xor(mx, off));
  if (lane == 0) redv[wid] = mx;
  __syncthreads();
  if (tid == 0)
    s_max = fmaxf(fmaxf(redv[0], redv[1]), fmaxf(redv[2], redv[3]));
  __syncthreads();
  mx = s_max;
  float se = 0.f, st = 0.f;
#pragma unroll
  for (int j2 = 0; j2 < 8; ++j2) { se += expf(lv[j2] - mx); st += lv[j2]; }
  for (int off = 32; off; off >>= 1) se += __shfl_xor(se, off);
  if (lane == 0) redv[wid] = se;
  __syncthreads();
  if (tid == 0) s_inv = 1.f / (redv[0] + redv[1] + redv[2] + redv[3]);
  __syncthreads();
  if (blockIdx.x == 0 && blockIdx.y == 0) {
    for (int off = 32; off; off >>= 1) st += __shfl_xor(st, off);
    if (lane == 0) redv[wid] = st;
    __syncthreads();
    if (tid == 0)
      meanT_out[0] = (redv[0] + redv[1] + redv[2] + redv[3]) * (1.f / 2048.f);
  }
  int mc = blockIdx.y;
  if (tid < 128) wl[tid] = expf(tens[mc * 128 + tid] - mx) * s_inv;
  __syncthreads();
  int j = blockIdx.x * 256 + tid;
  const float* src = (j < 512) ? ore : oim;
  int col = j & 511;
  float s = 0.f;
  for (int i = 0; i < 128; ++i) {
    int m = mc * 128 + i;
    s += wl[i] * src[(size_t)m * D_OUT + col];
  }
  cpart[(size_t)mc * 1024 + j] = s;
}

// ---------------- pred stage1 (comb reduction fused in) ----------------
__global__ __launch_bounds__(256) void k_pred_part(
    const float* __restrict__ cpart, const float* __restrict__ oh_w,
    float* __restrict__ ppart) {
  __shared__ float combs[128];
  int tid = threadIdx.x;
  int jc = blockIdx.y;
  if (tid < 128) {
    float s = 0.f;
#pragma unroll
    for (int mc = 0; mc < 16; ++mc) s += cpart[(size_t)mc * 1024 + jc * 128 + tid];
    combs[tid] = s;
  }
  __syncthreads();
  int n = blockIdx.x * 256 + tid;
  float s = 0.f;
#pragma unroll 8
  for (int i = 0; i < 128; ++i)
    s += combs[i] * oh_w[(size_t)(jc * 128 + i) * D_IN + n];
  ppart[(size_t)jc * D_IN + n] = s;
}

__global__ __launch_bounds__(256) void k_pred_red(
    const float* __restrict__ ppart, const float* __restrict__ oh_b,
    float* __restrict__ pred) {
  int n = blockIdx.x * 256 + threadIdx.x;
  float s = oh_b[n];
#pragma unroll
  for (int jc = 0; jc < 8; ++jc) s += ppart[(size_t)jc * D_IN + n];
  pred[n] = s;
}

// ---------------- launcher ----------------
extern "C" void kernel_launch(void* const* d_in, const int* in_sizes, int n_in,
                              void* d_out, int out_size, void* d_ws, size_t ws_size,
                              hipStream_t stream) {
  const float* x     = (const float*)d_in[0];
  const float* h_re  = (const float*)d_in[1];
  const float* h_im  = (const float*)d_in[2];
  const float* ea_wr = (const float*)d_in[3];
  const float* ea_br = (const float*)d_in[4];
  const float* ea_wi = (const float*)d_in[5];
  const float* ea_bi = (const float*)d_in[6];
  const float* eg_wr = (const float*)d_in[7];
  const float* eg_br = (const float*)d_in[8];
  const float* eg_wi = (const float*)d_in[9];
  const float* eg_bi = (const float*)d_in[10];
  const float* gz_w  = (const float*)d_in[11];
  const float* gz_b  = (const float*)d_in[12];
  const float* gr_w  = (const float*)d_in[13];
  const float* gr_b  = (const float*)d_in[14];
  const float* ghr_w = (const float*)d_in[15];
  const float* ghr_b = (const float*)d_in[16];
  const float* ghi_w = (const float*)d_in[17];
  const float* ghi_b = (const float*)d_in[18];
  const float* oh_w  = (const float*)d_in[19];
  const float* oh_b  = (const float*)d_in[20];
  const int*   step  = (const int*)d_in[21];

  float* out = (float*)d_out;
  float* pred_out  = out;
  float* meanT_out = out + 512;
  float* nhre_out  = out + 513;
  float* nhim_out  = out + 513 + N_CELLS * D_HID;

  char* p = (char*)d_ws;
  auto carve = [&](size_t bytes) { char* r = p; p += (bytes + 255) & ~(size_t)255; return r; };
  short* wdrT   = (short*)carve(512 * 1024 * 2);
  short* wdiT   = (short*)carve(512 * 1024 * 2);
  short* gzwT   = (short*)carve(1024 * 1536 * 2);
  short* grwT   = (short*)carve(1024 * 1536 * 2);
  short* ghrwT  = (short*)carve(1024 * 1536 * 2);
  short* ghiwT  = (short*)carve(1024 * 1536 * 2);
  short* hbre   = (short*)carve(2048 * 1024 * 2);
  short* hbim   = (short*)carve(2048 * 1024 * 2);
  short* gatesA = (short*)carve((size_t)2048 * 1536 * 2);
  short* candAre= (short*)carve((size_t)2048 * 1536 * 2);
  short* candAim= (short*)carve((size_t)2048 * 1536 * 2);
  float* ore    = (float*)carve(2048 * 512 * 4);
  float* oim    = (float*)carve(2048 * 512 * 4);
  float* zbuf   = (float*)carve((size_t)2048 * 1024 * 4);
  float* bpartr = (float*)carve(8 * 512 * 4);
  float* bparti = (float*)carve(8 * 512 * 4);
  float* tens   = (float*)carve(2048 * 4);
  float* fpart  = (float*)carve(2 * 64 * 1024 * 4);
  float* fsre   = (float*)carve(8 * 1024 * 4);
  float* fsim   = (float*)carve(8 * 1024 * 4);
  float* gre    = (float*)carve(1024 * 4);
  float* gim    = (float*)carve(1024 * 4);
  float* cpart  = (float*)carve(16 * 1024 * 4);
  float* ppart  = (float*)carve(8 * 512 * 4);

  hipLaunchKernelGGL(k_transpose_all, dim3(48, 32, 5), dim3(256), 0, stream,
                     gz_w, gr_w, ghr_w, ghi_w, gzwT, grwT, ghrwT, ghiwT,
                     ea_wr, eg_wr, ea_wi, eg_wi, wdrT, wdiT);
  hipLaunchKernelGGL(k_prep_h, dim3(2048), dim3(256), 0, stream,
                     h_re, h_im, hbre, hbim, gatesA, tens);
  hipLaunchKernelGGL(k_bias_part, dim3(2, 8), dim3(256), 0, stream,
                     x, ea_wr, ea_wi, eg_wr, eg_wi, bpartr, bparti);
  hipLaunchKernelGGL(k_engine, dim3(32, 8), dim3(256), 0, stream,
                     hbre, hbim, wdrT, wdiT, bpartr, bparti,
                     ea_br, ea_bi, eg_br, eg_bi,
                     ore, oim, gatesA, candAre, candAim, tens);
  hipLaunchKernelGGL(k_gates, dim3(16, 16), dim3(512), 0, stream,
                     gatesA, gzwT, grwT, gz_w, gz_b, gr_w, gr_b, tens,
                     h_re, h_im, zbuf, candAre, candAim);
  hipLaunchKernelGGL(k_cand, dim3(16, 8, 2), dim3(512), 0, stream,
                     candAre, candAim, ghrwT, ghiwT, ghr_b, ghi_b, ghr_w,
                     tens, zbuf, h_re, h_im, nhre_out, nhim_out);
  hipLaunchKernelGGL(k_fsum_part, dim3(64, 2), dim3(256), 0, stream,
                     nhre_out, nhim_out, fpart);
  hipLaunchKernelGGL(k_fsum_red, dim3(4, 2), dim3(256), 0, stream,
                     fpart, fsre, fsim, gre, gim);
  hipLaunchKernelGGL(k_sync, dim3((N_CELLS * D_HID) / 256), dim3(256), 0, stream,
                     nhre_out, nhim_out, fsre, fsim, gre, gim, step);
  hipLaunchKernelGGL(k_comb_part, dim3(4, 16), dim3(256), 0, stream,
                     ore, oim, tens, cpart, meanT_out);
  hipLaunchKernelGGL(k_pred_part, dim3(2, 8), dim3(256), 0, stream, cpart, oh_w, ppart);
  hipLaunchKernelGGL(k_pred_red, dim3(2), dim3(256), 0, stream, ppart, oh_b, pred_out);
}

// Round 11
// 281.015 us; speedup vs baseline: 1.1463x; 1.0329x over previous
//
#include <hip/hip_runtime.h>
#include <math.h>

#define N_CELLS 2048
#define D_IN 512
#define D_HID 1024
#define D_OUT 512

typedef __attribute__((ext_vector_type(8))) short bf16x8;
typedef __attribute__((ext_vector_type(4))) float f32x4;
typedef __attribute__((ext_vector_type(4))) short short4v;

#define MFMA16(a, b, c) __builtin_amdgcn_mfma_f32_16x16x32_bf16(a, b, c, 0, 0, 0)

__device__ __forceinline__ short f2bf(float f) {
  union { float f; unsigned u; } v; v.f = f;
  unsigned r = (v.u + 0x7FFFu + ((v.u >> 16) & 1u)) >> 16;
  return (short)r;
}

__device__ __forceinline__ void gl_lds16(const void* g, void* l) {
  __builtin_amdgcn_global_load_lds(
      (const __attribute__((address_space(1))) void*)g,
      (__attribute__((address_space(3))) void*)l, 16, 0, 0);
}

#define VMCNT(n) asm volatile("s_waitcnt vmcnt(" #n ")" ::: "memory")
#define BARRIER() asm volatile("s_barrier" ::: "memory")

// LDS bank-conflict swizzle (proven 0-conflict in R6): slot' = slot ^ ((row>>1)&3)
// applied on global SOURCE of global_load_lds (dest linear) and on ds_read slot.
#define SWZ(kq, row) ((kq) ^ (((row) >> 1) & 3))

// ---------------- merged prep: transposes (z<5) + prep_h (z=5,6) + bias_part (z=7)
__global__ __launch_bounds__(256) void k_prep(
    const float* __restrict__ w0, const float* __restrict__ w1,
    const float* __restrict__ w2, const float* __restrict__ w3,
    short* __restrict__ t0, short* __restrict__ t1,
    short* __restrict__ t2, short* __restrict__ t3,
    const float* __restrict__ ea_wr, const float* __restrict__ eg_wr,
    const float* __restrict__ ea_wi, const float* __restrict__ eg_wi,
    short* __restrict__ wdrT, short* __restrict__ wdiT,
    const float* __restrict__ h_re, const float* __restrict__ h_im,
    short* __restrict__ hbre, short* __restrict__ hbim, short* __restrict__ gatesA,
    float* __restrict__ tens,
    const float* __restrict__ x,
    float* __restrict__ bpartr, float* __restrict__ bparti) {
  const int zz = blockIdx.z;
  if (zz < 4) {
    const int k0 = blockIdx.x * 32, n0 = blockIdx.y * 32;
    const int c = threadIdx.x & 31, r4 = threadIdx.x >> 5;
    const int nl = threadIdx.x >> 3, kq = threadIdx.x & 7;
    const float* w = (zz == 0) ? w0 : (zz == 1) ? w1 : (zz == 2) ? w2 : w3;
    short* wT = (zz == 0) ? t0 : (zz == 1) ? t1 : (zz == 2) ? t2 : t3;
    __shared__ float t[32][33];
#pragma unroll
    for (int i = 0; i < 4; ++i) {
      int kl = r4 * 4 + i;
      int k = k0 + kl;
      int srcrow = (k < 512) ? k : k + 1;
      t[kl][c] = w[(size_t)srcrow * D_HID + n0 + c];
    }
    __syncthreads();
    short4v v;
#pragma unroll
    for (int jv = 0; jv < 4; ++jv) v[jv] = f2bf(t[kq * 4 + jv][nl]);
    *(short4v*)&wT[(size_t)(n0 + nl) * 1536 + k0 + kq * 4] = v;
  } else if (zz == 4) {
    if (blockIdx.x >= 32 || blockIdx.y >= 16) return;
    const int k0 = blockIdx.x * 32, n0 = blockIdx.y * 32;
    const int c = threadIdx.x & 31, r4 = threadIdx.x >> 5;
    const int nl = threadIdx.x >> 3, kq = threadIdx.x & 7;
    __shared__ float tr[32][33], ti[32][33];
#pragma unroll
    for (int i = 0; i < 4; ++i) {
      int kl = r4 * 4 + i;
      int src = (512 + k0 + kl) * D_OUT + n0 + c;
      tr[kl][c] = ea_wr[src] - eg_wr[src];
      ti[kl][c] = ea_wi[src] - eg_wi[src];
    }
    __syncthreads();
    short4v vr, vi;
#pragma unroll
    for (int jv = 0; jv < 4; ++jv) {
      vr[jv] = f2bf(tr[kq * 4 + jv][nl]);
      vi[jv] = f2bf(ti[kq * 4 + jv][nl]);
    }
    size_t dst = (size_t)(n0 + nl) * D_HID + k0 + kq * 4;
    *(short4v*)&wdrT[dst] = vr;
    *(short4v*)&wdiT[dst] = vi;
  } else if (zz < 7) {
    // prep_h: linear block p over two z-slices of 1536 blocks each
    int p = (zz - 5) * 1536 + blockIdx.y * 48 + blockIdx.x;
    if (p >= 2048) return;
    if (threadIdx.x == 0) tens[p] = 0.f;
    int idx4 = (p * 256 + threadIdx.x) * 4;
    int m = idx4 >> 10, n = idx4 & 1023;
    float4 hr = *(const float4*)&h_re[idx4];
    float4 hi = *(const float4*)&h_im[idx4];
    short4v br, bi, bm;
    br.x = f2bf(hr.x); br.y = f2bf(hr.y); br.z = f2bf(hr.z); br.w = f2bf(hr.w);
    bi.x = f2bf(hi.x); bi.y = f2bf(hi.y); bi.z = f2bf(hi.z); bi.w = f2bf(hi.w);
    bm.x = f2bf(sqrtf(hr.x * hr.x + hi.x * hi.x));
    bm.y = f2bf(sqrtf(hr.y * hr.y + hi.y * hi.y));
    bm.z = f2bf(sqrtf(hr.z * hr.z + hi.z * hi.z));
    bm.w = f2bf(sqrtf(hr.w * hr.w + hi.w * hi.w));
    *(short4v*)&hbre[idx4] = br;
    *(short4v*)&hbim[idx4] = bi;
    *(short4v*)&gatesA[(size_t)m * 1536 + 512 + n] = bm;
  } else {
    // bias_part: 16 blocks
    int p = blockIdx.y * 48 + blockIdx.x;
    if (p >= 16) return;
    int bx = p & 1, kc = p >> 1;
    int n = bx * 256 + threadIdx.x;
    float sr = 0.f, si = 0.f;
    for (int i = 0; i < 64; ++i) {
      int k = kc * 64 + i;
      float xv = x[k];
      int idx = k * D_OUT + n;
      sr += xv * (ea_wr[idx] - eg_wr[idx]);
      si += xv * (ea_wi[idx] - eg_wi[idx]);
    }
    bpartr[kc * D_OUT + n] = sr;
    bparti[kc * D_OUT + n] = si;
  }
}

// ---------------- MFMA GEMM 1: complex engine, tile 64x64, BK=64 ----------------
__global__ __launch_bounds__(256) void k_engine(
    const short* __restrict__ hbre, const short* __restrict__ hbim,
    const short* __restrict__ wdrT, const short* __restrict__ wdiT,
    const float* __restrict__ bpartr, const float* __restrict__ bparti,
    const float* __restrict__ ea_br, const float* __restrict__ ea_bi,
    const float* __restrict__ eg_br, const float* __restrict__ eg_bi,
    float* __restrict__ ore, float* __restrict__ oim,
    short* __restrict__ gatesA, short* __restrict__ candAre, short* __restrict__ candAim,
    float* __restrict__ tens) {
  __shared__ short Ar[2][4096], Ai[2][4096];
  __shared__ short Brs[2][4096], Bis[2][4096];
  const int m0 = blockIdx.x * 64, n0 = blockIdx.y * 64;
  const int tid = threadIdx.x;
  const int wid = tid >> 6, lane = tid & 63;
  const int quad = lane >> 4, lcol = lane & 15;
  const int wm = (wid >> 1) * 32, wn = (wid & 1) * 32;
  f32x4 accre[2][2], accim[2][2];
#pragma unroll
  for (int mt = 0; mt < 2; ++mt)
#pragma unroll
    for (int nt = 0; nt < 2; ++nt) {
      accre[mt][nt] = (f32x4){0.f, 0.f, 0.f, 0.f};
      accim[mt][nt] = (f32x4){0.f, 0.f, 0.f, 0.f};
    }
  auto stage = [&](int buf, int k0) {
#pragma unroll
    for (int i = 0; i < 2; ++i) {
      int c = i * 256 + tid;  // 0..511
      int kh = c >> 8, row = (c >> 2) & 63, kq = c & 3;
      size_t off = k0 + kh * 32 + SWZ(kq, row) * 8;
      size_t ga = (size_t)(m0 + row) * D_HID + off;
      size_t gb = (size_t)(n0 + row) * D_HID + off;
      gl_lds16(hbre + ga, &Ar[buf][c * 8]);
      gl_lds16(hbim + ga, &Ai[buf][c * 8]);
      gl_lds16(wdrT + gb, &Brs[buf][c * 8]);
      gl_lds16(wdiT + gb, &Bis[buf][c * 8]);
    }
  };
  stage(0, 0);
  for (int t = 0; t < 16; ++t) {
    const int cur = t & 1;
    if (t < 15) {
      stage(cur ^ 1, (t + 1) * 64);
      VMCNT(8);
    } else {
      VMCNT(0);
    }
    BARRIER();
#pragma unroll
    for (int kh = 0; kh < 2; ++kh) {
      bf16x8 ar[2], ai[2], ain[2], br[2], bi[2];
#pragma unroll
      for (int mt = 0; mt < 2; ++mt) {
        int row = wm + mt * 16 + lcol;
        int aoff = kh * 2048 + row * 32 + SWZ(quad, row) * 8;
        ar[mt] = *(const bf16x8*)&Ar[cur][aoff];
        ai[mt] = *(const bf16x8*)&Ai[cur][aoff];
#pragma unroll
        for (int jj = 0; jj < 8; ++jj) ain[mt][jj] = ai[mt][jj] ^ (short)0x8000;
      }
#pragma unroll
      for (int nt = 0; nt < 2; ++nt) {
        int row = wn + nt * 16 + lcol;
        int boff = kh * 2048 + row * 32 + SWZ(quad, row) * 8;
        br[nt] = *(const bf16x8*)&Brs[cur][boff];
        bi[nt] = *(const bf16x8*)&Bis[cur][boff];
      }
#pragma unroll
      for (int mt = 0; mt < 2; ++mt)
#pragma unroll
        for (int nt = 0; nt < 2; ++nt) {
          accre[mt][nt] = MFMA16(ar[mt], br[nt], accre[mt][nt]);
          accre[mt][nt] = MFMA16(ain[mt], bi[nt], accre[mt][nt]);
          accim[mt][nt] = MFMA16(ar[mt], bi[nt], accim[mt][nt]);
          accim[mt][nt] = MFMA16(ai[mt], br[nt], accim[mt][nt]);
        }
    }
    if (t < 15) BARRIER();
  }
  float bre[2], bim[2];
#pragma unroll
  for (int nt = 0; nt < 2; ++nt) {
    int n = n0 + wn + nt * 16 + lcol;
    float sr = 0.f, si = 0.f;
#pragma unroll
    for (int kc = 0; kc < 8; ++kc) {
      sr += bpartr[kc * D_OUT + n];
      si += bparti[kc * D_OUT + n];
    }
    float brd = ea_br[n] - eg_br[n];
    float bid = ea_bi[n] - eg_bi[n];
    bre[nt] = sr + brd - bid;
    bim[nt] = si + brd + bid;
  }
#pragma unroll
  for (int mt = 0; mt < 2; ++mt)
#pragma unroll
    for (int r = 0; r < 4; ++r) {
      int m = m0 + wm + mt * 16 + quad * 4 + r;
      float t = 0.f;
#pragma unroll
      for (int nt = 0; nt < 2; ++nt) {
        int n = n0 + wn + nt * 16 + lcol;
        float cre = accre[mt][nt][r] + bre[nt];
        float cim = accim[mt][nt][r] + bim[nt];
        t += cre * cre + cim * cim;
        ore[(size_t)m * D_OUT + n] = cre;
        oim[(size_t)m * D_OUT + n] = cim;
        gatesA[(size_t)m * 1536 + n] = f2bf(sqrtf(cre * cre + cim * cim));
        candAre[(size_t)m * 1536 + n] = f2bf(cre);
        candAim[(size_t)m * 1536 + n] = f2bf(cim);
      }
#pragma unroll
      for (int off = 1; off < 16; off <<= 1) t += __shfl_xor(t, off);
      if (lcol == 0) atomicAdd(&tens[m], t * (1.f / 512.f));
    }
}

// ---------------- MFMA GEMM 2: gates z+r FUSED, tile 128x64, SPLIT-K=2 (R10) ---
__global__ __launch_bounds__(512) void k_gates(
    const short* __restrict__ gatesA,
    const short* __restrict__ gzwT, const short* __restrict__ grwT,
    const float* __restrict__ gz_w, const float* __restrict__ gz_b,
    const float* __restrict__ gr_w, const float* __restrict__ gr_b,
    const float* __restrict__ tens,
    const float* __restrict__ h_re, const float* __restrict__ h_im,
    float* __restrict__ zbuf,
    short* __restrict__ candAre, short* __restrict__ candAim) {
  __shared__ short As[2][2][8192];
  __shared__ short Bzs[2][2][4096];
  __shared__ short Brs[2][2][4096];
  const int m0 = blockIdx.x * 128, n0 = blockIdx.y * 64;
  const int tid = threadIdx.x;
  const int wid = tid >> 6, lane = tid & 63;
  const int quad = lane >> 4, lcol = lane & 15;
  const int kg = wid >> 2, ws = wid & 3;
  const int wm = (ws >> 1) * 64, wn = (ws & 1) * 32;
  f32x4 accz[4][2], accr[4][2];
#pragma unroll
  for (int mt = 0; mt < 4; ++mt)
#pragma unroll
    for (int nt = 0; nt < 2; ++nt) {
      accz[mt][nt] = (f32x4){0.f, 0.f, 0.f, 0.f};
      accr[mt][nt] = (f32x4){0.f, 0.f, 0.f, 0.f};
    }
  auto stage = [&](int buf, int t) {
#pragma unroll
    for (int i = 0; i < 4; ++i) {
      int c = i * 512 + tid;
      int kgs = c >> 10, rem = c & 1023;
      int kh = rem >> 9, row = (rem >> 2) & 127, kq = rem & 3;
      gl_lds16(gatesA + (size_t)(m0 + row) * 1536 + kgs * 768 + t * 64 +
                   kh * 32 + SWZ(kq, row) * 8,
               &As[buf][kgs][rem * 8]);
    }
#pragma unroll
    for (int i = 0; i < 4; ++i) {
      int j = i * 512 + tid;
      int bsel = j >> 10, rem = j & 1023;
      int kgs = rem >> 9, r2 = rem & 511;
      int kh = r2 >> 8, row = (r2 >> 2) & 63, kq = r2 & 3;
      size_t g = (size_t)(n0 + row) * 1536 + kgs * 768 + t * 64 +
                 kh * 32 + SWZ(kq, row) * 8;
      if (bsel == 0) gl_lds16(gzwT + g, &Bzs[buf][kgs][r2 * 8]);
      else           gl_lds16(grwT + g, &Brs[buf][kgs][r2 * 8]);
    }
  };
  stage(0, 0);
  for (int t = 0; t < 12; ++t) {
    const int cur = t & 1;
    if (t < 11) {
      stage(cur ^ 1, t + 1);
      VMCNT(8);
    } else {
      VMCNT(0);
    }
    BARRIER();
#pragma unroll
    for (int kh = 0; kh < 2; ++kh) {
      bf16x8 a[4], bz[2], br[2];
#pragma unroll
      for (int mt = 0; mt < 4; ++mt) {
        int row = wm + mt * 16 + lcol;
        a[mt] = *(const bf16x8*)&As[cur][kg][kh * 4096 + row * 32 + SWZ(quad, row) * 8];
      }
#pragma unroll
      for (int nt = 0; nt < 2; ++nt) {
        int row = wn + nt * 16 + lcol;
        int boff = kh * 2048 + row * 32 + SWZ(quad, row) * 8;
        bz[nt] = *(const bf16x8*)&Bzs[cur][kg][boff];
        br[nt] = *(const bf16x8*)&Brs[cur][kg][boff];
      }
#pragma unroll
      for (int mt = 0; mt < 4; ++mt)
#pragma unroll
        for (int nt = 0; nt < 2; ++nt) {
          accz[mt][nt] = MFMA16(a[mt], bz[nt], accz[mt][nt]);
          accr[mt][nt] = MFMA16(a[mt], br[nt], accr[mt][nt]);
        }
    }
    if (t < 11) BARRIER();
  }
  float* red = (float*)&As[0][0][0];
  const int rbase = ws * 4096;
  BARRIER();
  if (kg == 1) {
#pragma unroll
    for (int mt = 0; mt < 4; ++mt)
#pragma unroll
      for (int nt = 0; nt < 2; ++nt)
#pragma unroll
        for (int r = 0; r < 4; ++r) {
          int idx = rbase + ((mt * 2 + nt) * 4 + r) * 64 + lane;
          red[idx] = accz[mt][nt][r];
          red[idx + 2048] = accr[mt][nt][r];
        }
  }
  BARRIER();
  if (kg == 0) {
#pragma unroll
    for (int mt = 0; mt < 4; ++mt)
#pragma unroll
      for (int nt = 0; nt < 2; ++nt)
#pragma unroll
        for (int r = 0; r < 4; ++r) {
          int idx = rbase + ((mt * 2 + nt) * 4 + r) * 64 + lane;
          int m = m0 + wm + mt * 16 + quad * 4 + r;
          int n = n0 + wn + nt * 16 + lcol;
          float tv = tens[m];
          float zp = accz[mt][nt][r] + red[idx] + gz_b[n] +
                     tv * gz_w[(size_t)512 * D_HID + n];
          zbuf[(size_t)m * D_HID + n] = 1.f / (1.f + expf(-zp));
          float rp = accr[mt][nt][r] + red[idx + 2048] + gr_b[n] +
                     tv * gr_w[(size_t)512 * D_HID + n];
          float rr = 1.f / (1.f + expf(-rp));
          candAre[(size_t)m * 1536 + 512 + n] = f2bf(rr * h_re[(size_t)m * D_HID + n]);
          candAim[(size_t)m * 1536 + 512 + n] = f2bf(rr * h_im[(size_t)m * D_HID + n]);
        }
  }
}

// ---------------- MFMA GEMM 3: candidate + GRU blend, tile 128x128 (R9 form) ---
__global__ __launch_bounds__(512) void k_cand(
    const short* __restrict__ candAre, const short* __restrict__ candAim,
    const short* __restrict__ ghrwT, const short* __restrict__ ghiwT,
    const float* __restrict__ ghr_b, const float* __restrict__ ghi_b,
    const float* __restrict__ ghr_w,
    const float* __restrict__ tens, const float* __restrict__ zbuf,
    const float* __restrict__ h_re, const float* __restrict__ h_im,
    float* __restrict__ nhre, float* __restrict__ nhim) {
  __shared__ short As[2][8192];
  __shared__ short Bs[2][8192];
  const int is_re = (blockIdx.z == 0);
  const short* A = is_re ? candAre : candAim;
  const short* Bt = is_re ? ghrwT : ghiwT;
  const float* bias = is_re ? ghr_b : ghi_b;
  const float* h = is_re ? h_re : h_im;
  float* outp = is_re ? nhre : nhim;
  const int m0 = blockIdx.x * 128, n0 = blockIdx.y * 128;
  const int tid = threadIdx.x;
  const int wid = tid >> 6, lane = tid & 63;
  const int quad = lane >> 4, lcol = lane & 15;
  const int wm = (wid >> 2) * 64, wn = (wid & 3) * 32;
  f32x4 acc[4][2];
#pragma unroll
  for (int mt = 0; mt < 4; ++mt)
#pragma unroll
    for (int nt = 0; nt < 2; ++nt) acc[mt][nt] = (f32x4){0.f, 0.f, 0.f, 0.f};
  auto stage = [&](int buf, int k0) {
#pragma unroll
    for (int i = 0; i < 2; ++i) {
      int c = i * 512 + tid;  // 0..1023
      int kh = c >> 9, row = (c >> 2) & 127, kq = c & 3;
      size_t off = k0 + kh * 32 + SWZ(kq, row) * 8;
      gl_lds16(A + (size_t)(m0 + row) * 1536 + off, &As[buf][c * 8]);
      gl_lds16(Bt + (size_t)(n0 + row) * 1536 + off, &Bs[buf][c * 8]);
    }
  };
  stage(0, 0);
  for (int t = 0; t < 24; ++t) {
    const int cur = t & 1;
    if (t < 23) {
      stage(cur ^ 1, (t + 1) * 64);
      VMCNT(4);
    } else {
      VMCNT(0);
    }
    BARRIER();
#pragma unroll
    for (int kh = 0; kh < 2; ++kh) {
      bf16x8 a[4], b[2];
#pragma unroll
      for (int mt = 0; mt < 4; ++mt) {
        int row = wm + mt * 16 + lcol;
        a[mt] = *(const bf16x8*)&As[cur][kh * 4096 + row * 32 + SWZ(quad, row) * 8];
      }
#pragma unroll
      for (int nt = 0; nt < 2; ++nt) {
        int row = wn + nt * 16 + lcol;
        b[nt] = *(const bf16x8*)&Bs[cur][kh * 4096 + row * 32 + SWZ(quad, row) * 8];
      }
#pragma unroll
      for (int mt = 0; mt < 4; ++mt)
#pragma unroll
        for (int nt = 0; nt < 2; ++nt)
          acc[mt][nt] = MFMA16(a[mt], b[nt], acc[mt][nt]);
    }
    if (t < 23) BARRIER();
  }
#pragma unroll
  for (int mt = 0; mt < 4; ++mt)
#pragma unroll
    for (int nt = 0; nt < 2; ++nt)
#pragma unroll
      for (int r = 0; r < 4; ++r) {
        int m = m0 + wm + mt * 16 + quad * 4 + r;
        int n = n0 + wn + nt * 16 + lcol;
        float pre = acc[mt][nt][r] + bias[n];
        if (is_re) pre += tens[m] * ghr_w[(size_t)512 * D_HID + n];
        float cand = tanhf(pre);
        float z = zbuf[(size_t)m * D_HID + n];
        float hv = h[(size_t)m * D_HID + n];
        outp[(size_t)m * D_HID + n] = (1.f - z) * hv + z * cand;
      }
}

// ---------------- faction sync: two-stage ----------------
__global__ __launch_bounds__(256) void k_fsum_part(
    const float* __restrict__ nhre, const float* __restrict__ nhim,
    float* __restrict__ fpart) {
  int f = blockIdx.x >> 3, rc = blockIdx.x & 7, comp = blockIdx.y;
  const float* src = comp ? nhim : nhre;
  int row0 = f * 256 + rc * 32;
#pragma unroll
  for (int nc = 0; nc < 4; ++nc) {
    int n = nc * 256 + threadIdx.x;
    float s = 0.f;
    const float* base = src + (size_t)row0 * D_HID + n;
    for (int jj = 0; jj < 32; ++jj) s += base[(size_t)jj * D_HID];
    fpart[((size_t)comp * 64 + blockIdx.x) * D_HID + n] = s;
  }
}

__global__ __launch_bounds__(256) void k_fsum_red(
    const float* __restrict__ fpart,
    float* __restrict__ fsre, float* __restrict__ fsim,
    float* __restrict__ gre, float* __restrict__ gim) {
  int n = blockIdx.x * 256 + threadIdx.x;
  int comp = blockIdx.y;
  float* fs = comp ? fsim : fsre;
  float* g = comp ? gim : gre;
  float gsum = 0.f;
#pragma unroll
  for (int f = 0; f < 8; ++f) {
    float sf = 0.f;
#pragma unroll
    for (int rc = 0; rc < 8; ++rc)
      sf += fpart[((size_t)comp * 64 + f * 8 + rc) * D_HID + n];
    fs[f * D_HID + n] = sf;
    gsum += sf;
  }
  g[n] = gsum * (1.f / 2048.f);
}

__global__ __launch_bounds__(256) void k_sync(
    float* __restrict__ nhre, float* __restrict__ nhim,
    const float* __restrict__ fsre, const float* __restrict__ fsim,
    const float* __restrict__ gre, const float* __restrict__ gim,
    const int* __restrict__ step) {
  int idx = blockIdx.x * 256 + threadIdx.x;
  int m = idx >> 10, n = idx & 1023;
  int f = m >> 8;
  float vr = nhre[idx], vi = nhim[idx];
  vr = 0.85f * vr + 0.15f * (fsre[f * D_HID + n] * (1.f / 256.f));
  vi = 0.85f * vi + 0.15f * (fsim[f * D_HID + n] * (1.f / 256.f));
  if (step[0] > 5 && (m & 255) < 64) {
    vr = 0.85f * vr + 0.15f * gre[n];
    vi = 0.85f * vi + 0.15f * gim[n];
  }
  nhre[idx] = vr;
  nhim[idx] = vi;
}

// ---------------- combine stage1 with fused softmax stats ----------------
__global__ __launch_bounds__(256) void k_comb_part(
    const float* __restrict__ ore, const float* __restrict__ oim,
    const float* __restrict__ tens, float* __restrict__ cpart,
    float* __restrict__ meanT_out) {
  __shared__ float redv[4];
  __shared__ float s_max, s_inv;
  __shared__ float wl[128];
  int tid = threadIdx.x;
  int wid = tid >> 6, lane = tid & 63;
  float lv[8];
  float mx = -1e30f;
#pragma unroll
  for (int j2 = 0; j2 < 8; ++j2) {
    lv[j2] = tens[tid + j2 * 256];
    mx = fmaxf(mx, lv[j2]);
  }
  for (int off = 32; off; off >>= 1) mx = fmaxf(mx, __shfl_xor(mx, off));
  if (lane == 0) redv[wid] = mx;
  __syncthreads();
  if (tid == 0)
    s_max = fmaxf(fmaxf(redv[0], redv[1]), fmaxf(redv[2], redv[3]));
  __syncthreads();
  mx = s_max;
  float se = 0.f, st = 0.f;
#pragma unroll
  for (int j2 = 0; j2 < 8; ++j2) { se += expf(lv[j2] - mx); st += lv[j2]; }
  for (int off = 32; off; off >>= 1) se += __shfl_xor(se, off);
  if (lane == 0) redv[wid] = se;
  __syncthreads();
  if (tid == 0) s_inv = 1.f / (redv[0] + redv[1] + redv[2] + redv[3]);
  __syncthreads();
  if (blockIdx.x == 0 && blockIdx.y == 0) {
    for (int off = 32; off; off >>= 1) st += __shfl_xor(st, off);
    if (lane == 0) redv[wid] = st;
    __syncthreads();
    if (tid == 0)
      meanT_out[0] = (redv[0] + redv[1] + redv[2] + redv[3]) * (1.f / 2048.f);
  }
  int mc = blockIdx.y;
  if (tid < 128) wl[tid] = expf(tens[mc * 128 + tid] - mx) * s_inv;
  __syncthreads();
  int j = blockIdx.x * 256 + tid;
  const float* src = (j < 512) ? ore : oim;
  int col = j & 511;
  float s = 0.f;
  for (int i = 0; i < 128; ++i) {
    int m = mc * 128 + i;
    s += wl[i] * src[(size_t)m * D_OUT + col];
  }
  cpart[(size_t)mc * 1024 + j] = s;
}

// ---------------- pred stage1 (comb reduction fused in) ----------------
__global__ __launch_bounds__(256) void k_pred_part(
    const float* __restrict__ cpart, const float* __restrict__ oh_w,
    float* __restrict__ ppart) {
  __shared__ float combs[128];
  int tid = threadIdx.x;
  int jc = blockIdx.y;
  if (tid < 128) {
    float s = 0.f;
#pragma unroll
    for (int mc = 0; mc < 16; ++mc) s += cpart[(size_t)mc * 1024 + jc * 128 + tid];
    combs[tid] = s;
  }
  __syncthreads();
  int n = blockIdx.x * 256 + tid;
  float s = 0.f;
#pragma unroll 8
  for (int i = 0; i < 128; ++i)
    s += combs[i] * oh_w[(size_t)(jc * 128 + i) * D_IN + n];
  ppart[(size_t)jc * D_IN + n] = s;
}

__global__ __launch_bounds__(256) void k_pred_red(
    const float* __restrict__ ppart, const float* __restrict__ oh_b,
    float* __restrict__ pred) {
  int n = blockIdx.x * 256 + threadIdx.x;
  float s = oh_b[n];
#pragma unroll
  for (int jc = 0; jc < 8; ++jc) s += ppart[(size_t)jc * D_IN + n];
  pred[n] = s;
}

// ---------------- launcher ----------------
extern "C" void kernel_launch(void* const* d_in, const int* in_sizes, int n_in,
                              void* d_out, int out_size, void* d_ws, size_t ws_size,
                              hipStream_t stream) {
  const float* x     = (const float*)d_in[0];
  const float* h_re  = (const float*)d_in[1];
  const float* h_im  = (const float*)d_in[2];
  const float* ea_wr = (const float*)d_in[3];
  const float* ea_br = (const float*)d_in[4];
  const float* ea_wi = (const float*)d_in[5];
  const float* ea_bi = (const float*)d_in[6];
  const float* eg_wr = (const float*)d_in[7];
  const float* eg_br = (const float*)d_in[8];
  const float* eg_wi = (const float*)d_in[9];
  const float* eg_bi = (const float*)d_in[10];
  const float* gz_w  = (const float*)d_in[11];
  const float* gz_b  = (const float*)d_in[12];
  const float* gr_w  = (const float*)d_in[13];
  const float* gr_b  = (const float*)d_in[14];
  const float* ghr_w = (const float*)d_in[15];
  const float* ghr_b = (const float*)d_in[16];
  const float* ghi_w = (const float*)d_in[17];
  const float* ghi_b = (const float*)d_in[18];
  const float* oh_w  = (const float*)d_in[19];
  const float* oh_b  = (const float*)d_in[20];
  const int*   step  = (const int*)d_in[21];

  float* out = (float*)d_out;
  float* pred_out  = out;
  float* meanT_out = out + 512;
  float* nhre_out  = out + 513;
  float* nhim_out  = out + 513 + N_CELLS * D_HID;

  char* p = (char*)d_ws;
  auto carve = [&](size_t bytes) { char* r = p; p += (bytes + 255) & ~(size_t)255; return r; };
  short* wdrT   = (short*)carve(512 * 1024 * 2);
  short* wdiT   = (short*)carve(512 * 1024 * 2);
  short* gzwT   = (short*)carve(1024 * 1536 * 2);
  short* grwT   = (short*)carve(1024 * 1536 * 2);
  short* ghrwT  = (short*)carve(1024 * 1536 * 2);
  short* ghiwT  = (short*)carve(1024 * 1536 * 2);
  short* hbre   = (short*)carve(2048 * 1024 * 2);
  short* hbim   = (short*)carve(2048 * 1024 * 2);
  short* gatesA = (short*)carve((size_t)2048 * 1536 * 2);
  short* candAre= (short*)carve((size_t)2048 * 1536 * 2);
  short* candAim= (short*)carve((size_t)2048 * 1536 * 2);
  float* ore    = (float*)carve(2048 * 512 * 4);
  float* oim    = (float*)carve(2048 * 512 * 4);
  float* zbuf   = (float*)carve((size_t)2048 * 1024 * 4);
  float* bpartr = (float*)carve(8 * 512 * 4);
  float* bparti = (float*)carve(8 * 512 * 4);
  float* tens   = (float*)carve(2048 * 4);
  float* fpart  = (float*)carve(2 * 64 * 1024 * 4);
  float* fsre   = (float*)carve(8 * 1024 * 4);
  float* fsim   = (float*)carve(8 * 1024 * 4);
  float* gre    = (float*)carve(1024 * 4);
  float* gim    = (float*)carve(1024 * 4);
  float* cpart  = (float*)carve(16 * 1024 * 4);
  float* ppart  = (float*)carve(8 * 512 * 4);

  hipLaunchKernelGGL(k_prep, dim3(48, 32, 8), dim3(256), 0, stream,
                     gz_w, gr_w, ghr_w, ghi_w, gzwT, grwT, ghrwT, ghiwT,
                     ea_wr, eg_wr, ea_wi, eg_wi, wdrT, wdiT,
                     h_re, h_im, hbre, hbim, gatesA, tens,
                     x, bpartr, bparti);
  hipLaunchKernelGGL(k_engine, dim3(32, 8), dim3(256), 0, stream,
                     hbre, hbim, wdrT, wdiT, bpartr, bparti,
                     ea_br, ea_bi, eg_br, eg_bi,
                     ore, oim, gatesA, candAre, candAim, tens);
  hipLaunchKernelGGL(k_gates, dim3(16, 16), dim3(512), 0, stream,
                     gatesA, gzwT, grwT, gz_w, gz_b, gr_w, gr_b, tens,
                     h_re, h_im, zbuf, candAre, candAim);
  hipLaunchKernelGGL(k_cand, dim3(16, 8, 2), dim3(512), 0, stream,
                     candAre, candAim, ghrwT, ghiwT, ghr_b, ghi_b, ghr_w,
                     tens, zbuf, h_re, h_im, nhre_out, nhim_out);
  hipLaunchKernelGGL(k_fsum_part, dim3(64, 2), dim3(256), 0, stream,
                     nhre_out, nhim_out, fpart);
  hipLaunchKernelGGL(k_fsum_red, dim3(4, 2), dim3(256), 0, stream,
                     fpart, fsre, fsim, gre, gim);
  hipLaunchKernelGGL(k_sync, dim3((N_CELLS * D_HID) / 256), dim3(256), 0, stream,
                     nhre_out, nhim_out, fsre, fsim, gre, gim, step);
  hipLaunchKernelGGL(k_comb_part, dim3(4, 16), dim3(256), 0, stream,
                     ore, oim, tens, cpart, meanT_out);
  hipLaunchKernelGGL(k_pred_part, dim3(2, 8), dim3(256), 0, stream, cpart, oh_w, ppart);
  hipLaunchKernelGGL(k_pred_red, dim3(2), dim3(256), 0, stream, ppart, oh_b, pred_out);
}